// Round 2
// baseline (3129.867 us; speedup 1.0000x reference)
//
#include <hip/hip_runtime.h>
#include <math.h>

// ---------------------------------------------------------------------------
// RSSM: B=16, T=64 (bt=1024), encoder 3->32->64->128->256 (k4 s2 p1) with
// full-tensor LayerNorm+SiLU per layer, fc 4096->256, GRU(1030->128),
// prior 128->1024, post 384->1024, z = per-32-chunk argmax one-hot.
// All fp32: one flipped argmax = 1.0 error in z -> low precision in the
// logit path is fatal.
// R5 changes (from profile): conv3_r was 775us at 67% VALU / 1.7% HBM /
// 14% of fp32 FMA peak -- per-lane scattered input gathers (16 global loads
// per c, 64 lane addrs spanning ~16 cache lines each) saturated the L1/TA
// gather path. Now conv2/conv3 stage input channels into LDS with coalesced
// float4 loads (16 VMEM/thread vs 2048) and read windows via ds_read; oc
// register blocking widened to acc[32] per pass (statically indexed -- no
// spills) so input reads halve. Weights remain wave-uniform s_loads.
// ---------------------------------------------------------------------------

__device__ __forceinline__ float silu_f(float t){ return t / (1.f + __expf(-t)); }
__device__ __forceinline__ float sigm_f(float x){ return 1.f / (1.f + expf(-x)); }

// Block-level mean/rstd over m values; each thread contributes (s, s2).
__device__ __forceinline__ void block_stats_256(float s, float s2, int m,
                                                float& mean, float& rstd)
{
    __shared__ float red[8];
#pragma unroll
    for (int off = 32; off > 0; off >>= 1) {
        s  += __shfl_down(s, off);
        s2 += __shfl_down(s2, off);
    }
    int wv = threadIdx.x >> 6;
    if ((threadIdx.x & 63) == 0) { red[wv] = s; red[4 + wv] = s2; }
    __syncthreads();
    if (threadIdx.x == 0) {
        float S  = (red[0] + red[1]) + (red[2] + red[3]);
        float S2 = (red[4] + red[5]) + (red[6] + red[7]);
        float mu = S / m;
        float var = S2 / m - mu * mu;
        red[0] = mu;
        red[1] = rsqrtf(var + 1e-5f);
    }
    __syncthreads();
    mean = red[0]; rstd = red[1];
}

// ---------------- fused LayerNorm+SiLU, one block per sample ---------------
__global__ __launch_bounds__(256) void ln_fuse_k(float* __restrict__ x,
    const float* __restrict__ g, const float* __restrict__ b, int m)
{
    int n = blockIdx.x;
    float* p = x + (size_t)n * m;
    float s = 0.f, s2 = 0.f;
    for (int i = threadIdx.x * 4; i < m; i += 1024) {
        float4 v = *(const float4*)(p + i);
        s  += (v.x + v.y) + (v.z + v.w);
        s2 += (v.x*v.x + v.y*v.y) + (v.z*v.z + v.w*v.w);
    }
    float mean, rstd;
    block_stats_256(s, s2, m, mean, rstd);
    for (int i = threadIdx.x * 4; i < m; i += 1024) {
        float4 v  = *(float4*)(p + i);
        float4 gv = *(const float4*)(g + i);
        float4 bv = *(const float4*)(b + i);
        v.x = silu_f((v.x - mean) * rstd * gv.x + bv.x);
        v.y = silu_f((v.y - mean) * rstd * gv.y + bv.y);
        v.z = silu_f((v.z - mean) * rstd * gv.z + bv.z);
        v.w = silu_f((v.w - mean) * rstd * gv.w + bv.w);
        *(float4*)(p + i) = v;
    }
}

// ------------------------- conv1: 3x64x64 -> 32x32x32 ----------------------
__global__ __launch_bounds__(256) void conv1_k(const float* __restrict__ in,
    const float* __restrict__ w, const float* __restrict__ bias, float* __restrict__ out)
{
    int n  = blockIdx.x;                 // chunk-local sample
    int yq = blockIdx.y;                 // 4 y-quarters
    int tx = threadIdx.x & 31;
    int ty = threadIdx.x >> 5;           // 0..7
    int y  = yq * 8 + ty;                // 0..31
    const float* ip = in + (size_t)n * 12288;

    float okf[16]; int offs[16];
#pragma unroll
    for (int ky = 0; ky < 4; ky++) {
        int yy = 2 * y - 1 + ky;
        bool yok = ((unsigned)yy < 64u);
#pragma unroll
        for (int kx = 0; kx < 4; kx++) {
            int xx = 2 * tx - 1 + kx;
            bool ok = yok && ((unsigned)xx < 64u);
            okf[ky*4+kx]  = ok ? 1.f : 0.f;
            offs[ky*4+kx] = ok ? yy * 64 + xx : 0;
        }
    }
    float iv[48];
#pragma unroll
    for (int c = 0; c < 3; c++)
#pragma unroll
        for (int q = 0; q < 16; q++)
            iv[c*16+q] = ip[c*4096 + offs[q]] * okf[q];

    float* op = out + (size_t)n * 32768 + y * 32 + tx;
#pragma unroll 4
    for (int oc = 0; oc < 32; oc++) {           // oc uniform -> weights s_load
        float acc = bias[oc];
        const float* wp = w + oc * 48;
#pragma unroll
        for (int q = 0; q < 48; q++) acc += iv[q] * wp[q];
        op[oc * 1024] = acc;
    }
}

// ------- conv2: 32x32x32 -> 64x16x16, LDS-staged input, 2 passes of 32 -----
// Per chunk: 4 channels (16 KB) staged coalesced; per c: 16 ds_read + 512
// FMA per wave (acc[32], weights wave-uniform s_load).
__global__ __launch_bounds__(256) void conv2_r(const float* __restrict__ in,
    const float* __restrict__ w, const float* __restrict__ bias, float* __restrict__ out)
{
    __shared__ __align__(16) float lin[4096];     // 4 channels x 1024
    int n  = blockIdx.x;
    int tid = threadIdx.x;
    int tx = tid & 15, ty = tid >> 4;
    const float* ip = in + (size_t)n * 32768;

    float okf[16]; int offs[16];
#pragma unroll
    for (int ky = 0; ky < 4; ky++) {
        int yy = 2 * ty - 1 + ky;
        bool yok = ((unsigned)yy < 32u);
#pragma unroll
        for (int kx = 0; kx < 4; kx++) {
            int xx = 2 * tx - 1 + kx;
            bool ok = yok && ((unsigned)xx < 32u);
            okf[ky*4+kx]  = ok ? 1.f : 0.f;
            offs[ky*4+kx] = ok ? yy * 32 + xx : 0;
        }
    }
    float* op = out + (size_t)n * 16384 + tid;
#pragma unroll 1
    for (int p = 0; p < 2; p++) {
        float acc[32];
#pragma unroll
        for (int i = 0; i < 32; i++) acc[i] = bias[p * 32 + i];
#pragma unroll 1
        for (int ch = 0; ch < 8; ch++) {          // 8 chunks of 4 channels
            const float4* gsrc = (const float4*)(ip + (ch << 12));
            float4* ldst = (float4*)lin;
#pragma unroll
            for (int k = 0; k < 4; k++)
                ldst[tid + (k << 8)] = gsrc[tid + (k << 8)];   // coalesced 1KB/inst
            __syncthreads();
            for (int cl = 0; cl < 4; cl++) {
                int c = (ch << 2) + cl;
                const float* icp = lin + (cl << 10);
                float iv[16];
#pragma unroll
                for (int q = 0; q < 16; q++) iv[q] = icp[offs[q]] * okf[q];
#pragma unroll
                for (int i = 0; i < 32; i++) {
                    const float* wp = w + (size_t)(p * 32 + i) * 512 + c * 16;  // uniform
#pragma unroll
                    for (int q = 0; q < 16; q++) acc[i] += iv[q] * wp[q];
                }
            }
            __syncthreads();
        }
#pragma unroll
        for (int i = 0; i < 32; i++) op[(p * 32 + i) * 256] = acc[i];
    }
}

// ------- conv3: 64x16x16 -> 128x8x8, LDS-staged input, wave=32oc, 1 pass ---
// Per chunk: 8 channels (8 KB) staged coalesced; per c: 16 ds_read + 512
// FMA per wave (acc[32], weights wave-uniform s_load).
__global__ __launch_bounds__(256) void conv3_r(const float* __restrict__ in,
    const float* __restrict__ w, const float* __restrict__ bias, float* __restrict__ out)
{
    __shared__ __align__(16) float lin[2048];     // 8 channels x 256
    int n   = blockIdx.x;
    int tid = threadIdx.x;
    int ocb = __builtin_amdgcn_readfirstlane((tid >> 6) << 5);  // wave id * 32
    int s0 = tid & 63, y = s0 >> 3, x = s0 & 7;
    const float* ip = in + (size_t)n * 16384;

    float okf[16]; int offs[16];
#pragma unroll
    for (int ky = 0; ky < 4; ky++) {
        int yy = 2 * y - 1 + ky;
        bool yok = ((unsigned)yy < 16u);
#pragma unroll
        for (int kx = 0; kx < 4; kx++) {
            int xx = 2 * x - 1 + kx;
            bool ok = yok && ((unsigned)xx < 16u);
            okf[ky*4+kx]  = ok ? 1.f : 0.f;
            offs[ky*4+kx] = ok ? yy * 16 + xx : 0;
        }
    }
    float acc[32];
#pragma unroll
    for (int i = 0; i < 32; i++) acc[i] = bias[ocb + i];

#pragma unroll 1
    for (int ch = 0; ch < 8; ch++) {              // 8 chunks of 8 channels
        const float4* gsrc = (const float4*)(ip + (ch << 11));
        float4* ldst = (float4*)lin;
#pragma unroll
        for (int k = 0; k < 2; k++)
            ldst[tid + (k << 8)] = gsrc[tid + (k << 8)];       // coalesced 1KB/inst
        __syncthreads();
        for (int cl = 0; cl < 8; cl++) {
            int c = (ch << 3) + cl;
            const float* icp = lin + (cl << 8);
            float iv[16];
#pragma unroll
            for (int q = 0; q < 16; q++) iv[q] = icp[offs[q]] * okf[q];
#pragma unroll
            for (int i = 0; i < 32; i++) {
                const float* wp = w + ((size_t)(ocb + i) * 64 + c) * 16;  // wave-uniform
#pragma unroll
                for (int q = 0; q < 16; q++) acc[i] += iv[q] * wp[q];
            }
        }
        __syncthreads();
    }
    float* op = out + (size_t)n * 8192 + s0;
#pragma unroll
    for (int i = 0; i < 32; i++) op[(ocb + i) * 64] = acc[i];
}

// ----------------- conv4 + LN4 + SiLU: 128x8x8 -> 256x4x4 ------------------
__global__ __launch_bounds__(256) void conv4_f(const float* __restrict__ in,
    const float* __restrict__ w, const float* __restrict__ bias,
    const float* __restrict__ g, const float* __restrict__ bet, float* __restrict__ out)
{
    int n  = blockIdx.x;
    int oc = threadIdx.x;                 // 0..255
    const float* ip = in + (size_t)n * 8192;
    const float* wr = w + (size_t)oc * 2048;

    float acc[16];
#pragma unroll
    for (int s = 0; s < 16; s++) acc[s] = bias[oc];

    for (int c = 0; c < 128; c++) {
        const float* ic = ip + c * 64;     // uniform base -> s_load, CSE'd
        const float* wc = wr + c * 16;
        float wf[16];
#pragma unroll
        for (int q = 0; q < 16; q += 4) {
            float4 v = *(const float4*)(wc + q);
            wf[q] = v.x; wf[q+1] = v.y; wf[q+2] = v.z; wf[q+3] = v.w;
        }
#pragma unroll
        for (int y = 0; y < 4; y++)
#pragma unroll
        for (int x = 0; x < 4; x++) {
            float a = acc[y * 4 + x];
#pragma unroll
            for (int ky = 0; ky < 4; ky++) {
                int yy = 2 * y - 1 + ky;
                if (yy < 0 || yy > 7) continue;      // folds at compile time
#pragma unroll
                for (int kx = 0; kx < 4; kx++) {
                    int xx = 2 * x - 1 + kx;
                    if (xx < 0 || xx > 7) continue;
                    a += wf[ky * 4 + kx] * ic[yy * 8 + xx];
                }
            }
            acc[y * 4 + x] = a;
        }
    }
    float s = 0.f, s2 = 0.f;
#pragma unroll
    for (int q = 0; q < 16; q++) { s += acc[q]; s2 += acc[q] * acc[q]; }
    float mean, rstd;
    block_stats_256(s, s2, 4096, mean, rstd);

    float* op = out + (size_t)n * 4096;
#pragma unroll
    for (int q = 0; q < 16; q++) {
        int flat = oc * 16 + q;
        float v = (acc[q] - mean) * rstd * g[flat] + bet[flat];
        op[flat] = silu_f(v);
    }
}

// -------- transpose fc_w [256][4096] -> fcwT [4096][256] (LDS-tiled) -------
__global__ __launch_bounds__(256) void trfc_k(const float* __restrict__ w,
                                              float* __restrict__ wt)
{
    __shared__ float t[32][33];
    int bk = blockIdx.x * 32;             // k dim (4096)
    int bj = blockIdx.y * 32;             // j dim (256)
    int lx = threadIdx.x & 31, ly = threadIdx.x >> 5;   // 32 x 8
#pragma unroll
    for (int s = 0; s < 4; s++)
        t[ly + 8*s][lx] = w[(size_t)(bj + ly + 8*s) * 4096 + bk + lx];
    __syncthreads();
#pragma unroll
    for (int s = 0; s < 4; s++)
        wt[(size_t)(bk + ly + 8*s) * 256 + bj + lx] = t[lx][ly + 8*s];
}

// ---------------- fc: [S,4096] @ wT[4096][256], coalesced ------------------
__global__ __launch_bounds__(256) void fc_k2(const float* __restrict__ a,
    const float* __restrict__ wT, const float* __restrict__ bias, float* __restrict__ o)
{
    int n0 = blockIdx.x * 8;              // chunk-local rows
    int j  = threadIdx.x;
    float acc[8];
#pragma unroll
    for (int r = 0; r < 8; r++) acc[r] = 0.f;
    for (int k = 0; k < 4096; k += 4) {
        float wv0 = wT[(size_t)k * 256 + j];
        float wv1 = wT[(size_t)(k+1) * 256 + j];
        float wv2 = wT[(size_t)(k+2) * 256 + j];
        float wv3 = wT[(size_t)(k+3) * 256 + j];
#pragma unroll
        for (int r = 0; r < 8; r++) {
            const float* ar = a + (size_t)(n0 + r) * 4096 + k;   // uniform -> s_load x4
            acc[r] += wv0*ar[0] + wv1*ar[1] + wv2*ar[2] + wv3*ar[3];
        }
    }
    float bj = bias[j];
#pragma unroll
    for (int r = 0; r < 8; r++) o[(size_t)(n0 + r) * 256 + j] = acc[r] + bj;
}

// ----------- Fpost[n,j] = post_b[j] + feats[n,:] @ post_w[j,128:384] -------
__global__ __launch_bounds__(256) void fpost_k(const float* __restrict__ f,
    const float* __restrict__ w, const float* __restrict__ bias, float* __restrict__ o)
{
    int n0 = blockIdx.x * 4;
    int tid = threadIdx.x;
    float acc[4][4];
#pragma unroll
    for (int r = 0; r < 4; r++)
#pragma unroll
        for (int jj = 0; jj < 4; jj++) acc[r][jj] = 0.f;
    for (int k = 0; k < 256; k += 4) {
        float4 wv[4];
#pragma unroll
        for (int jj = 0; jj < 4; jj++)
            wv[jj] = *(const float4*)(w + (size_t)(tid + jj * 256) * 384 + 128 + k);
#pragma unroll
        for (int r = 0; r < 4; r++) {
            const float* fr = f + (size_t)(n0 + r) * 256 + k;    // uniform
            float a0 = fr[0], a1 = fr[1], a2 = fr[2], a3 = fr[3];
#pragma unroll
            for (int jj = 0; jj < 4; jj++)
                acc[r][jj] += wv[jj].x*a0 + wv[jj].y*a1 + wv[jj].z*a2 + wv[jj].w*a3;
        }
    }
#pragma unroll
    for (int jj = 0; jj < 4; jj++) {
        float bj = bias[tid + jj * 256];
#pragma unroll
        for (int r = 0; r < 4; r++)
            o[(size_t)(n0 + r) * 1024 + tid + jj * 256] = acc[r][jj] + bj;
    }
}

// ----------- prior[n,j] = prior_b[j] + h[n,:] @ prior_w[j,:] ---------------
__global__ __launch_bounds__(256) void prior_k(const float* __restrict__ h,
    const float* __restrict__ w, const float* __restrict__ bias, float* __restrict__ o)
{
    int n0 = blockIdx.x * 4;
    int tid = threadIdx.x;
    float acc[4][4];
#pragma unroll
    for (int r = 0; r < 4; r++)
#pragma unroll
        for (int jj = 0; jj < 4; jj++) acc[r][jj] = 0.f;
    for (int k = 0; k < 128; k += 4) {
        float4 wv[4];
#pragma unroll
        for (int jj = 0; jj < 4; jj++)
            wv[jj] = *(const float4*)(w + (size_t)(tid + jj * 256) * 128 + k);
#pragma unroll
        for (int r = 0; r < 4; r++) {
            const float* hr = h + (size_t)(n0 + r) * 128 + k;    // uniform
            float a0 = hr[0], a1 = hr[1], a2 = hr[2], a3 = hr[3];
#pragma unroll
            for (int jj = 0; jj < 4; jj++)
                acc[r][jj] += wv[jj].x*a0 + wv[jj].y*a1 + wv[jj].z*a2 + wv[jj].w*a3;
        }
    }
#pragma unroll
    for (int jj = 0; jj < 4; jj++) {
        float bj = bias[tid + jj * 256];
#pragma unroll
        for (int r = 0; r < 4; r++)
            o[(size_t)(n0 + r) * 1024 + tid + jj * 256] = acc[r][jj] + bj;
    }
}

// ----------- Ai[n,j] = bih[j] + actions[n,:] @ wih[j,1024:1030] ------------
__global__ __launch_bounds__(128) void ai_k(const float* __restrict__ act,
    const float* __restrict__ wih, const float* __restrict__ bih, float* __restrict__ o)
{
    int n = blockIdx.x;
    int j = blockIdx.y * 128 + threadIdx.x;     // 0..383
    const float* ar = act + (size_t)n * 6;       // uniform
    const float* wr = wih + (size_t)j * 1030 + 1024;
    float acc = bih[j];
#pragma unroll
    for (int k = 0; k < 6; k++) acc += ar[k] * wr[k];
    o[(size_t)n * 384 + j] = acc;
}

// ----------- wihT[k,j] = wih[j,k]  (z-part only, k<1024) -------------------
__global__ __launch_bounds__(256) void tr_k(const float* __restrict__ wih,
                                            float* __restrict__ wt)
{
    int g = blockIdx.x * 256 + threadIdx.x;      // 0..393215
    int k = g / 384;
    int j = g - k * 384;
    wt[g] = wih[(size_t)j * 1030 + k];
}

// ----------- whhT[k,j] = whh[j,k]  ([128][384] from [384][128]) ------------
__global__ __launch_bounds__(256) void tr_whh_k(const float* __restrict__ whh,
                                                float* __restrict__ wt)
{
    int g = blockIdx.x * 256 + threadIdx.x;      // 0..49151
    int k = g / 384;
    int j = g - k * 384;
    wt[g] = whh[(size_t)j * 128 + k];
}

// ----------- pwTh[k,j] = post_w[j,k] (h-cols only, k<128) ------------------
__global__ __launch_bounds__(256) void tr_pw_k(const float* __restrict__ pw,
                                               float* __restrict__ wt)
{
    int g = blockIdx.x * 256 + threadIdx.x;      // 0..131071
    int k = g >> 10;
    int j = g & 1023;
    wt[g] = pw[(size_t)j * 384 + k];
}

// ------------------------- GRU recurrence (1 block / sample) ---------------
// R4: transposed weights (whhT [128][384], pwTh [128][1024]) -> every weight
// load is wave-coalesced; h read as float4 from LDS; post stage 2 outputs/
// thread; argmax as in-register 32-lane shfl_xor butterfly.
__global__ __launch_bounds__(1024) void gru_k(const float* __restrict__ wihT,
    const float* __restrict__ whhT, const float* __restrict__ bhh,
    const float* __restrict__ ai, const float* __restrict__ fpost,
    const float* __restrict__ pwTh, float* __restrict__ out)
{
    float* out_post = out + 1048576;
    float* out_h    = out + 2097152;
    float* out_z    = out + 2228224;
    int b   = blockIdx.x;
    int tid = threadIdx.x;
    __shared__ __align__(16) float h[128];
    __shared__ float gi[384], gh[384];
    __shared__ int idx[32];
    if (tid < 128) h[tid] = 0.f;
    __syncthreads();

    for (int t = 0; t < 64; t++) {
        int n = b * 64 + t;
        if (tid < 384) {
            float a = ai[(size_t)n * 384 + tid];
            if (t > 0) {
#pragma unroll 8
                for (int c = 0; c < 32; c++)
                    a += wihT[(size_t)(c * 32 + idx[c]) * 384 + tid];
            }
            gi[tid] = a;
            float a2 = bhh[tid];
            const float* wc = whhT + tid;            // coalesced column walk
#pragma unroll 8
            for (int k = 0; k < 128; k += 4) {
                float4 hv = *(const float4*)(h + k); // ds_read_b128 broadcast
                a2 += wc[(size_t)k * 384]       * hv.x
                    + wc[(size_t)(k + 1) * 384] * hv.y
                    + wc[(size_t)(k + 2) * 384] * hv.z
                    + wc[(size_t)(k + 3) * 384] * hv.w;
            }
            gh[tid] = a2;
        }
        __syncthreads();                                    // B1
        if (tid < 128) {
            float r  = sigm_f(gi[tid] + gh[tid]);
            float u  = sigm_f(gi[128 + tid] + gh[128 + tid]);
            float nn = tanhf(gi[256 + tid] + r * gh[256 + tid]);
            float hn = (1.f - u) * nn + u * h[tid];
            h[tid] = hn;
            out_h[(size_t)n * 128 + tid] = hn;
        }
        __syncthreads();                                    // B2
        if (tid < 512) {
            // outputs j0 = tid, j1 = tid + 512 (chunks c0 = tid>>5, c0+16)
            float a0 = fpost[(size_t)n * 1024 + tid];
            float a1 = fpost[(size_t)n * 1024 + 512 + tid];
            const float* wc0 = pwTh + tid;           // coalesced column walk
            const float* wc1 = pwTh + 512 + tid;
#pragma unroll 8
            for (int k = 0; k < 128; k += 4) {
                float4 hv = *(const float4*)(h + k); // reused for both outputs
                size_t o0 = (size_t)k * 1024;
                a0 += wc0[o0]        * hv.x + wc0[o0 + 1024] * hv.y
                    + wc0[o0 + 2048] * hv.z + wc0[o0 + 3072] * hv.w;
                a1 += wc1[o0]        * hv.x + wc1[o0 + 1024] * hv.y
                    + wc1[o0 + 2048] * hv.z + wc1[o0 + 3072] * hv.w;
            }
            out_post[(size_t)n * 1024 + tid]       = a0;
            out_post[(size_t)n * 1024 + 512 + tid] = a1;

            // first-max argmax over each 32-lane chunk, in-register butterfly
            float b0 = a0, b1 = a1;
            int i0 = tid & 31, i1 = tid & 31;
#pragma unroll
            for (int m = 16; m >= 1; m >>= 1) {
                float ob0 = __shfl_xor(b0, m);
                int   oi0 = __shfl_xor(i0, m);
                float ob1 = __shfl_xor(b1, m);
                int   oi1 = __shfl_xor(i1, m);
                if (ob0 > b0 || (ob0 == b0 && oi0 < i0)) { b0 = ob0; i0 = oi0; }
                if (ob1 > b1 || (ob1 == b1 && oi1 < i1)) { b1 = ob1; i1 = oi1; }
            }
            out_z[(size_t)n * 1024 + tid]       = ((tid & 31) == i0) ? 1.f : 0.f;
            out_z[(size_t)n * 1024 + 512 + tid] = ((tid & 31) == i1) ? 1.f : 0.f;
            if ((tid & 31) == 0) {
                idx[tid >> 5]        = i0;
                idx[(tid >> 5) + 16] = i1;
            }
        }
        __syncthreads();                                    // B3
    }
}

// ---------------------------------------------------------------------------
extern "C" void kernel_launch(void* const* d_in, const int* in_sizes, int n_in,
                              void* d_out, int out_size, void* d_ws, size_t ws_size,
                              hipStream_t stream)
{
    const float* states  = (const float*)d_in[0];
    const float* actions = (const float*)d_in[1];
    const float* c1w = (const float*)d_in[2];  const float* c1b = (const float*)d_in[3];
    const float* l1g = (const float*)d_in[4];  const float* l1b = (const float*)d_in[5];
    const float* c2w = (const float*)d_in[6];  const float* c2b = (const float*)d_in[7];
    const float* l2g = (const float*)d_in[8];  const float* l2b = (const float*)d_in[9];
    const float* c3w = (const float*)d_in[10]; const float* c3b = (const float*)d_in[11];
    const float* l3g = (const float*)d_in[12]; const float* l3b = (const float*)d_in[13];
    const float* c4w = (const float*)d_in[14]; const float* c4b = (const float*)d_in[15];
    const float* l4g = (const float*)d_in[16]; const float* l4b = (const float*)d_in[17];
    const float* fcw = (const float*)d_in[18]; const float* fcb = (const float*)d_in[19];
    const float* wih = (const float*)d_in[20]; const float* whh = (const float*)d_in[21];
    const float* bih = (const float*)d_in[22]; const float* bhh = (const float*)d_in[23];
    const float* prw = (const float*)d_in[24]; const float* prb = (const float*)d_in[25];
    const float* pw  = (const float*)d_in[26]; const float* pb  = (const float*)d_in[27];

    float* out = (float*)d_out;
    float* ws  = (float*)d_ws;

    // ---- adaptive chunking: largest S whose footprint fits ws_size --------
    // footprint = (S*49152 + fixed 3,325,952) floats
    size_t S = 64;
    {
        const size_t cands[4] = {1024, 512, 256, 128};
        for (int i = 0; i < 4; i++) {
            size_t need = (cands[i] * 49152ull + 3325952ull) * 4ull;
            if (need <= ws_size) { S = cands[i]; break; }
        }
    }
    int C = (int)(1024 / S);

    float* bufA  = ws;                       // S*32768
    float* bufB  = bufA + S * 32768;         // S*16384
    float* feats = bufB + S * 16384;         //   262,144
    float* fpost = feats + 262144;           // 1,048,576
    float* aibuf = fpost + 1048576;          //   393,216
    float* wihT  = aibuf + 393216;           //   393,216
    float* fcwT  = wihT + 393216;            // 1,048,576
    float* whhT  = fcwT + 1048576;           //    49,152
    float* pwTh  = whhT + 49152;             //   131,072

    trfc_k<<<dim3(128, 8), 256, 0, stream>>>(fcw, fcwT);
    tr_whh_k<<<192, 256, 0, stream>>>(whh, whhT);
    tr_pw_k<<<512, 256, 0, stream>>>(pw, pwTh);

    for (int cc = 0; cc < C; cc++) {
        size_t n0 = (size_t)cc * S;
        conv1_k<<<dim3((unsigned)S, 4), 256, 0, stream>>>(states + n0 * 12288, c1w, c1b, bufA);
        ln_fuse_k<<<(unsigned)S, 256, 0, stream>>>(bufA, l1g, l1b, 32768);
        conv2_r<<<(unsigned)S, 256, 0, stream>>>(bufA, c2w, c2b, bufB);
        ln_fuse_k<<<(unsigned)S, 256, 0, stream>>>(bufB, l2g, l2b, 16384);
        conv3_r<<<(unsigned)S, 256, 0, stream>>>(bufB, c3w, c3b, bufA);
        ln_fuse_k<<<(unsigned)S, 256, 0, stream>>>(bufA, l3g, l3b, 8192);
        conv4_f<<<(unsigned)S, 256, 0, stream>>>(bufA, c4w, c4b, l4g, l4b, bufB);
        fc_k2<<<(unsigned)(S / 8), 256, 0, stream>>>(bufB, fcwT, fcb, feats + n0 * 256);
    }

    fpost_k<<<256, 256, 0, stream>>>(feats, pw, pb, fpost);
    ai_k<<<dim3(1024, 3), 128, 0, stream>>>(actions, wih, bih, aibuf);
    tr_k<<<1536, 256, 0, stream>>>(wih, wihT);

    gru_k<<<16, 1024, 0, stream>>>(wihT, whhT, bhh, aibuf, fpost, pwTh, out);
    prior_k<<<256, 256, 0, stream>>>(out + 2097152, prw, prb, out);
}

// Round 3
// 2705.216 us; speedup vs baseline: 1.1570x; 1.1570x over previous
//
#include <hip/hip_runtime.h>
#include <math.h>

// ---------------------------------------------------------------------------
// RSSM: B=16, T=64 (bt=1024), encoder 3->32->64->128->256 (k4 s2 p1) with
// full-tensor LayerNorm+SiLU per layer, fc 4096->256, GRU(1030->128),
// prior 128->1024, post 384->1024, z = per-32-chunk argmax one-hot.
// All fp32: one flipped argmax = 1.0 error in z -> low precision in the
// logit path is fatal.
// R6 changes (from profile): conv2_r unchanged at 706us after R5's input
// staging -> input gathers were never the bottleneck; the 1:1 FMA:weight
// fetch ratio was (each 16-FMA group waits on its own weight fetch, 2048
// dependent groups/wave). Now conv2/conv3 stage WEIGHTS in LDS too, read
// them as wave-uniform broadcast ds_read_b128 (no conflict), and use
// 2 pos x 32 oc register tiles (acc[64], all-static) so each weight float4
// feeds 32 FMAs and input is staged exactly once. Input LDS rows carry a
// float4-granule rotation swizzle to keep window gathers ~2-4-way; invalid
// taps read a per-channel zero slot (no okf multiplies).
// ---------------------------------------------------------------------------

__device__ __forceinline__ float silu_f(float t){ return t / (1.f + __expf(-t)); }
__device__ __forceinline__ float sigm_f(float x){ return 1.f / (1.f + expf(-x)); }

// Block-level mean/rstd over m values; each thread contributes (s, s2).
__device__ __forceinline__ void block_stats_256(float s, float s2, int m,
                                                float& mean, float& rstd)
{
    __shared__ float red[8];
#pragma unroll
    for (int off = 32; off > 0; off >>= 1) {
        s  += __shfl_down(s, off);
        s2 += __shfl_down(s2, off);
    }
    int wv = threadIdx.x >> 6;
    if ((threadIdx.x & 63) == 0) { red[wv] = s; red[4 + wv] = s2; }
    __syncthreads();
    if (threadIdx.x == 0) {
        float S  = (red[0] + red[1]) + (red[2] + red[3]);
        float S2 = (red[4] + red[5]) + (red[6] + red[7]);
        float mu = S / m;
        float var = S2 / m - mu * mu;
        red[0] = mu;
        red[1] = rsqrtf(var + 1e-5f);
    }
    __syncthreads();
    mean = red[0]; rstd = red[1];
}

// ---------------- fused LayerNorm+SiLU, one block per sample ---------------
__global__ __launch_bounds__(256) void ln_fuse_k(float* __restrict__ x,
    const float* __restrict__ g, const float* __restrict__ b, int m)
{
    int n = blockIdx.x;
    float* p = x + (size_t)n * m;
    float s = 0.f, s2 = 0.f;
    for (int i = threadIdx.x * 4; i < m; i += 1024) {
        float4 v = *(const float4*)(p + i);
        s  += (v.x + v.y) + (v.z + v.w);
        s2 += (v.x*v.x + v.y*v.y) + (v.z*v.z + v.w*v.w);
    }
    float mean, rstd;
    block_stats_256(s, s2, m, mean, rstd);
    for (int i = threadIdx.x * 4; i < m; i += 1024) {
        float4 v  = *(float4*)(p + i);
        float4 gv = *(const float4*)(g + i);
        float4 bv = *(const float4*)(b + i);
        v.x = silu_f((v.x - mean) * rstd * gv.x + bv.x);
        v.y = silu_f((v.y - mean) * rstd * gv.y + bv.y);
        v.z = silu_f((v.z - mean) * rstd * gv.z + bv.z);
        v.w = silu_f((v.w - mean) * rstd * gv.w + bv.w);
        *(float4*)(p + i) = v;
    }
}

// ------------------------- conv1: 3x64x64 -> 32x32x32 ----------------------
__global__ __launch_bounds__(256) void conv1_k(const float* __restrict__ in,
    const float* __restrict__ w, const float* __restrict__ bias, float* __restrict__ out)
{
    int n  = blockIdx.x;                 // chunk-local sample
    int yq = blockIdx.y;                 // 4 y-quarters
    int tx = threadIdx.x & 31;
    int ty = threadIdx.x >> 5;           // 0..7
    int y  = yq * 8 + ty;                // 0..31
    const float* ip = in + (size_t)n * 12288;

    float okf[16]; int offs[16];
#pragma unroll
    for (int ky = 0; ky < 4; ky++) {
        int yy = 2 * y - 1 + ky;
        bool yok = ((unsigned)yy < 64u);
#pragma unroll
        for (int kx = 0; kx < 4; kx++) {
            int xx = 2 * tx - 1 + kx;
            bool ok = yok && ((unsigned)xx < 64u);
            okf[ky*4+kx]  = ok ? 1.f : 0.f;
            offs[ky*4+kx] = ok ? yy * 64 + xx : 0;
        }
    }
    float iv[48];
#pragma unroll
    for (int c = 0; c < 3; c++)
#pragma unroll
        for (int q = 0; q < 16; q++)
            iv[c*16+q] = ip[c*4096 + offs[q]] * okf[q];

    float* op = out + (size_t)n * 32768 + y * 32 + tx;
#pragma unroll 4
    for (int oc = 0; oc < 32; oc++) {           // oc uniform -> weights s_load
        float acc = bias[oc];
        const float* wp = w + oc * 48;
#pragma unroll
        for (int q = 0; q < 48; q++) acc += iv[q] * wp[q];
        op[oc * 1024] = acc;
    }
}

// ------- conv2: 32x32x32 -> 64x16x16 -------------------------------------
// Block = 1 sample, 256 thr. Wave pair -> oc half (32 oc); 128 pos-slots,
// thread = (y0,x) and (y0+8,x). LDS: [4ch: 4 zero + 1024 rot-swizzled] +
// [4ch x 64oc x 16 weights]. Inner: iv 32 b32 + weights broadcast b128.
__global__ __launch_bounds__(256) void conv2_r(const float* __restrict__ in,
    const float* __restrict__ w, const float* __restrict__ bias, float* __restrict__ out)
{
    __shared__ __align__(16) float lds[8208];     // 4*1028 input + 4096 wt
    int n  = blockIdx.x;
    int tid = threadIdx.x;
    int wv  = tid >> 6;
    int g   = wv >> 1;                            // oc half 0/1
    int s   = ((wv & 1) << 6) | (tid & 63);       // 0..127
    int x   = s & 15, y0 = s >> 4;                // x 0..15, y0 0..7
    const float* ip = in + (size_t)n * 32768;

    int offs[2][16];
#pragma unroll
    for (int p = 0; p < 2; p++) {
        int y = y0 + 8 * p;
#pragma unroll
        for (int ky = 0; ky < 4; ky++) {
            int yi = 2 * y - 1 + ky;
#pragma unroll
            for (int kx = 0; kx < 4; kx++) {
                int xi = 2 * x - 1 + kx;
                bool ok = ((unsigned)yi < 32u) && ((unsigned)xi < 32u);
                int rot = ((xi >> 2) + (yi & 7)) & 7;
                int foff = yi * 32 + rot * 4 + (xi & 3);
                offs[p][ky*4+kx] = ok ? (4 + foff) * 4 : 0;   // bytes; 0 = zero slot
            }
        }
    }
    if (tid < 16) lds[(tid >> 2) * 1028 + (tid & 3)] = 0.f;   // zero slots

    float acc0[32], acc1[32];
#pragma unroll
    for (int i = 0; i < 32; i++) { float bv = bias[g*32 + i]; acc0[i] = bv; acc1[i] = bv; }

#pragma unroll 1
    for (int ch = 0; ch < 8; ch++) {              // 8 chunks x 4 channels
        __syncthreads();
        {   // stage input: 4 ch x 1024 fl, rotated rows
            const float4* gs = (const float4*)(ip + (ch << 12));
#pragma unroll
            for (int k = 0; k < 4; k++) {
                int gid = tid + (k << 8);         // 0..1023 f4s
                int cc = gid >> 8, r = (gid >> 3) & 31, s4 = gid & 7;
                int rs = (s4 + (r & 7)) & 7;
                *(float4*)&lds[cc*1028 + 4 + r*32 + rs*4] = gs[gid];
            }
            // stage weights: 4 ch x 64 oc x 16
            int oc = tid >> 2, i4 = tid & 3;
            const float* wg = w + (size_t)oc * 512 + (ch << 6) + i4 * 4;
#pragma unroll
            for (int cc = 0; cc < 4; cc++)
                *(float4*)&lds[4112 + cc*1024 + oc*16 + i4*4] =
                    *(const float4*)(wg + cc * 16);
        }
        __syncthreads();
#pragma unroll 1
        for (int cc = 0; cc < 4; cc++) {
            const char* cb = (const char*)lds + cc * 4112;
            float iv0[16], iv1[16];
#pragma unroll
            for (int q = 0; q < 16; q++) {
                iv0[q] = *(const float*)(cb + offs[0][q]);
                iv1[q] = *(const float*)(cb + offs[1][q]);
            }
            const float* wb = &lds[4112 + cc*1024 + g*512];   // wave-uniform base
#pragma unroll
            for (int o = 0; o < 32; o++) {
                float wt[16];
                *(float4*)&wt[0]  = *(const float4*)(wb + o*16);
                *(float4*)&wt[4]  = *(const float4*)(wb + o*16 + 4);
                *(float4*)&wt[8]  = *(const float4*)(wb + o*16 + 8);
                *(float4*)&wt[12] = *(const float4*)(wb + o*16 + 12);
#pragma unroll
                for (int q = 0; q < 16; q++) {
                    acc0[o] = fmaf(iv0[q], wt[q], acc0[o]);
                    acc1[o] = fmaf(iv1[q], wt[q], acc1[o]);
                }
            }
        }
    }
    float* op = out + (size_t)n * 16384;
#pragma unroll
    for (int o = 0; o < 32; o++) {
        op[(g*32 + o) * 256 + y0*16 + x]       = acc0[o];
        op[(g*32 + o) * 256 + (y0+8)*16 + x]   = acc1[o];
    }
}

// ------- conv3: 64x16x16 -> 128x8x8 ---------------------------------------
// Block = 2 samples, 256 thr. Wave -> oc quarter (32 oc); lane = (sample,
// pos-pair). Same LDS weight-broadcast structure; 16 chunks x 4 channels.
__global__ __launch_bounds__(256) void conv3_r(const float* __restrict__ in,
    const float* __restrict__ w, const float* __restrict__ bias, float* __restrict__ out)
{
    __shared__ __align__(16) float lds[10272];    // 2*1040 input + 8192 wt
    int n0  = blockIdx.x * 2;
    int tid = threadIdx.x;
    int wv  = tid >> 6;
    int ocb = wv * 32;
    int lane = tid & 63;
    int sl  = lane >> 5, slot = lane & 31;
    int x   = slot & 7, y0 = slot >> 3;           // x 0..7, y0 0..3

    int offs[2][16];
#pragma unroll
    for (int p = 0; p < 2; p++) {
        int y = y0 + 4 * p;
#pragma unroll
        for (int ky = 0; ky < 4; ky++) {
            int yi = 2 * y - 1 + ky;
#pragma unroll
            for (int kx = 0; kx < 4; kx++) {
                int xi = 2 * x - 1 + kx;
                bool ok = ((unsigned)yi < 16u) && ((unsigned)xi < 16u);
                int rot = ((xi >> 2) + (yi & 3)) & 3;
                int foff = yi * 16 + rot * 4 + (xi & 3);
                offs[p][ky*4+kx] = ok ? (4 + foff) * 4 : 0;
            }
        }
    }
    if (tid < 32) {
        int ss = tid >> 4, cc = (tid >> 2) & 3, q = tid & 3;
        lds[ss*1040 + cc*260 + q] = 0.f;
    }
    float acc0[32], acc1[32];
#pragma unroll
    for (int i = 0; i < 32; i++) { float bv = bias[ocb + i]; acc0[i] = bv; acc1[i] = bv; }

    int sbase = sl * 4160;                        // byte base of my sample
#pragma unroll 1
    for (int ch = 0; ch < 16; ch++) {             // 16 chunks x 4 channels
        __syncthreads();
        {   // stage input: 2 samples x 4 ch x 256 fl
            int ts = tid >> 7, f = tid & 127;
            const float4* gs = (const float4*)(in + (size_t)(n0 + ts) * 16384 + (ch << 10));
#pragma unroll
            for (int k = 0; k < 2; k++) {
                int gid = f + (k << 7);           // 0..255 f4s
                int cc = gid >> 6, r = (gid >> 2) & 15, s4 = gid & 3;
                int rs = (s4 + (r & 3)) & 3;
                *(float4*)&lds[ts*1040 + cc*260 + 4 + r*16 + rs*4] = gs[gid];
            }
            // stage weights: 4 ch x 128 oc x 16
            int oc = tid >> 1, h = tid & 1;
            const float* wg = w + (size_t)oc * 1024 + (ch << 6) + h * 8;
#pragma unroll
            for (int cc = 0; cc < 4; cc++) {
                *(float4*)&lds[2080 + cc*2048 + oc*16 + h*8]     = *(const float4*)(wg + cc*16);
                *(float4*)&lds[2080 + cc*2048 + oc*16 + h*8 + 4] = *(const float4*)(wg + cc*16 + 4);
            }
        }
        __syncthreads();
#pragma unroll 1
        for (int cc = 0; cc < 4; cc++) {
            const char* cb = (const char*)lds + sbase + cc * 1040;
            float iv0[16], iv1[16];
#pragma unroll
            for (int q = 0; q < 16; q++) {
                iv0[q] = *(const float*)(cb + offs[0][q]);
                iv1[q] = *(const float*)(cb + offs[1][q]);
            }
            const float* wb = &lds[2080 + cc*2048 + ocb*16];  // wave-uniform base
#pragma unroll
            for (int o = 0; o < 32; o++) {
                float wt[16];
                *(float4*)&wt[0]  = *(const float4*)(wb + o*16);
                *(float4*)&wt[4]  = *(const float4*)(wb + o*16 + 4);
                *(float4*)&wt[8]  = *(const float4*)(wb + o*16 + 8);
                *(float4*)&wt[12] = *(const float4*)(wb + o*16 + 12);
#pragma unroll
                for (int q = 0; q < 16; q++) {
                    acc0[o] = fmaf(iv0[q], wt[q], acc0[o]);
                    acc1[o] = fmaf(iv1[q], wt[q], acc1[o]);
                }
            }
        }
    }
    float* op = out + (size_t)(n0 + sl) * 8192;
#pragma unroll
    for (int o = 0; o < 32; o++) {
        op[(ocb + o) * 64 + slot]      = acc0[o];
        op[(ocb + o) * 64 + slot + 32] = acc1[o];
    }
}

// ----------------- conv4 + LN4 + SiLU: 128x8x8 -> 256x4x4 ------------------
__global__ __launch_bounds__(256) void conv4_f(const float* __restrict__ in,
    const float* __restrict__ w, const float* __restrict__ bias,
    const float* __restrict__ g, const float* __restrict__ bet, float* __restrict__ out)
{
    int n  = blockIdx.x;
    int oc = threadIdx.x;                 // 0..255
    const float* ip = in + (size_t)n * 8192;
    const float* wr = w + (size_t)oc * 2048;

    float acc[16];
#pragma unroll
    for (int s = 0; s < 16; s++) acc[s] = bias[oc];

    for (int c = 0; c < 128; c++) {
        const float* ic = ip + c * 64;     // uniform base -> s_load, CSE'd
        const float* wc = wr + c * 16;
        float wf[16];
#pragma unroll
        for (int q = 0; q < 16; q += 4) {
            float4 v = *(const float4*)(wc + q);
            wf[q] = v.x; wf[q+1] = v.y; wf[q+2] = v.z; wf[q+3] = v.w;
        }
#pragma unroll
        for (int y = 0; y < 4; y++)
#pragma unroll
        for (int x = 0; x < 4; x++) {
            float a = acc[y * 4 + x];
#pragma unroll
            for (int ky = 0; ky < 4; ky++) {
                int yy = 2 * y - 1 + ky;
                if (yy < 0 || yy > 7) continue;      // folds at compile time
#pragma unroll
                for (int kx = 0; kx < 4; kx++) {
                    int xx = 2 * x - 1 + kx;
                    if (xx < 0 || xx > 7) continue;
                    a += wf[ky * 4 + kx] * ic[yy * 8 + xx];
                }
            }
            acc[y * 4 + x] = a;
        }
    }
    float s = 0.f, s2 = 0.f;
#pragma unroll
    for (int q = 0; q < 16; q++) { s += acc[q]; s2 += acc[q] * acc[q]; }
    float mean, rstd;
    block_stats_256(s, s2, 4096, mean, rstd);

    float* op = out + (size_t)n * 4096;
#pragma unroll
    for (int q = 0; q < 16; q++) {
        int flat = oc * 16 + q;
        float v = (acc[q] - mean) * rstd * g[flat] + bet[flat];
        op[flat] = silu_f(v);
    }
}

// -------- transpose fc_w [256][4096] -> fcwT [4096][256] (LDS-tiled) -------
__global__ __launch_bounds__(256) void trfc_k(const float* __restrict__ w,
                                              float* __restrict__ wt)
{
    __shared__ float t[32][33];
    int bk = blockIdx.x * 32;             // k dim (4096)
    int bj = blockIdx.y * 32;             // j dim (256)
    int lx = threadIdx.x & 31, ly = threadIdx.x >> 5;   // 32 x 8
#pragma unroll
    for (int s = 0; s < 4; s++)
        t[ly + 8*s][lx] = w[(size_t)(bj + ly + 8*s) * 4096 + bk + lx];
    __syncthreads();
#pragma unroll
    for (int s = 0; s < 4; s++)
        wt[(size_t)(bk + ly + 8*s) * 256 + bj + lx] = t[lx][ly + 8*s];
}

// ---------------- fc: [S,4096] @ wT[4096][256], coalesced ------------------
__global__ __launch_bounds__(256) void fc_k2(const float* __restrict__ a,
    const float* __restrict__ wT, const float* __restrict__ bias, float* __restrict__ o)
{
    int n0 = blockIdx.x * 8;              // chunk-local rows
    int j  = threadIdx.x;
    float acc[8];
#pragma unroll
    for (int r = 0; r < 8; r++) acc[r] = 0.f;
    for (int k = 0; k < 4096; k += 4) {
        float wv0 = wT[(size_t)k * 256 + j];
        float wv1 = wT[(size_t)(k+1) * 256 + j];
        float wv2 = wT[(size_t)(k+2) * 256 + j];
        float wv3 = wT[(size_t)(k+3) * 256 + j];
#pragma unroll
        for (int r = 0; r < 8; r++) {
            const float* ar = a + (size_t)(n0 + r) * 4096 + k;   // uniform -> s_load x4
            acc[r] += wv0*ar[0] + wv1*ar[1] + wv2*ar[2] + wv3*ar[3];
        }
    }
    float bj = bias[j];
#pragma unroll
    for (int r = 0; r < 8; r++) o[(size_t)(n0 + r) * 256 + j] = acc[r] + bj;
}

// ----------- Fpost[n,j] = post_b[j] + feats[n,:] @ post_w[j,128:384] -------
__global__ __launch_bounds__(256) void fpost_k(const float* __restrict__ f,
    const float* __restrict__ w, const float* __restrict__ bias, float* __restrict__ o)
{
    int n0 = blockIdx.x * 4;
    int tid = threadIdx.x;
    float acc[4][4];
#pragma unroll
    for (int r = 0; r < 4; r++)
#pragma unroll
        for (int jj = 0; jj < 4; jj++) acc[r][jj] = 0.f;
    for (int k = 0; k < 256; k += 4) {
        float4 wv[4];
#pragma unroll
        for (int jj = 0; jj < 4; jj++)
            wv[jj] = *(const float4*)(w + (size_t)(tid + jj * 256) * 384 + 128 + k);
#pragma unroll
        for (int r = 0; r < 4; r++) {
            const float* fr = f + (size_t)(n0 + r) * 256 + k;    // uniform
            float a0 = fr[0], a1 = fr[1], a2 = fr[2], a3 = fr[3];
#pragma unroll
            for (int jj = 0; jj < 4; jj++)
                acc[r][jj] += wv[jj].x*a0 + wv[jj].y*a1 + wv[jj].z*a2 + wv[jj].w*a3;
        }
    }
#pragma unroll
    for (int jj = 0; jj < 4; jj++) {
        float bj = bias[tid + jj * 256];
#pragma unroll
        for (int r = 0; r < 4; r++)
            o[(size_t)(n0 + r) * 1024 + tid + jj * 256] = acc[r][jj] + bj;
    }
}

// ----------- prior[n,j] = prior_b[j] + h[n,:] @ prior_w[j,:] ---------------
__global__ __launch_bounds__(256) void prior_k(const float* __restrict__ h,
    const float* __restrict__ w, const float* __restrict__ bias, float* __restrict__ o)
{
    int n0 = blockIdx.x * 4;
    int tid = threadIdx.x;
    float acc[4][4];
#pragma unroll
    for (int r = 0; r < 4; r++)
#pragma unroll
        for (int jj = 0; jj < 4; jj++) acc[r][jj] = 0.f;
    for (int k = 0; k < 128; k += 4) {
        float4 wv[4];
#pragma unroll
        for (int jj = 0; jj < 4; jj++)
            wv[jj] = *(const float4*)(w + (size_t)(tid + jj * 256) * 128 + k);
#pragma unroll
        for (int r = 0; r < 4; r++) {
            const float* hr = h + (size_t)(n0 + r) * 128 + k;    // uniform
            float a0 = hr[0], a1 = hr[1], a2 = hr[2], a3 = hr[3];
#pragma unroll
            for (int jj = 0; jj < 4; jj++)
                acc[r][jj] += wv[jj].x*a0 + wv[jj].y*a1 + wv[jj].z*a2 + wv[jj].w*a3;
        }
    }
#pragma unroll
    for (int jj = 0; jj < 4; jj++) {
        float bj = bias[tid + jj * 256];
#pragma unroll
        for (int r = 0; r < 4; r++)
            o[(size_t)(n0 + r) * 1024 + tid + jj * 256] = acc[r][jj] + bj;
    }
}

// ----------- Ai[n,j] = bih[j] + actions[n,:] @ wih[j,1024:1030] ------------
__global__ __launch_bounds__(128) void ai_k(const float* __restrict__ act,
    const float* __restrict__ wih, const float* __restrict__ bih, float* __restrict__ o)
{
    int n = blockIdx.x;
    int j = blockIdx.y * 128 + threadIdx.x;     // 0..383
    const float* ar = act + (size_t)n * 6;       // uniform
    const float* wr = wih + (size_t)j * 1030 + 1024;
    float acc = bih[j];
#pragma unroll
    for (int k = 0; k < 6; k++) acc += ar[k] * wr[k];
    o[(size_t)n * 384 + j] = acc;
}

// ----------- wihT[k,j] = wih[j,k]  (z-part only, k<1024) -------------------
__global__ __launch_bounds__(256) void tr_k(const float* __restrict__ wih,
                                            float* __restrict__ wt)
{
    int g = blockIdx.x * 256 + threadIdx.x;      // 0..393215
    int k = g / 384;
    int j = g - k * 384;
    wt[g] = wih[(size_t)j * 1030 + k];
}

// ----------- whhT[k,j] = whh[j,k]  ([128][384] from [384][128]) ------------
__global__ __launch_bounds__(256) void tr_whh_k(const float* __restrict__ whh,
                                                float* __restrict__ wt)
{
    int g = blockIdx.x * 256 + threadIdx.x;      // 0..49151
    int k = g / 384;
    int j = g - k * 384;
    wt[g] = whh[(size_t)j * 128 + k];
}

// ----------- pwTh[k,j] = post_w[j,k] (h-cols only, k<128) ------------------
__global__ __launch_bounds__(256) void tr_pw_k(const float* __restrict__ pw,
                                               float* __restrict__ wt)
{
    int g = blockIdx.x * 256 + threadIdx.x;      // 0..131071
    int k = g >> 10;
    int j = g & 1023;
    wt[g] = pw[(size_t)j * 384 + k];
}

// ------------------------- GRU recurrence (1 block / sample) ---------------
// R4: transposed weights (whhT [128][384], pwTh [128][1024]) -> every weight
// load is wave-coalesced; h read as float4 from LDS; post stage 2 outputs/
// thread; argmax as in-register 32-lane shfl_xor butterfly.
__global__ __launch_bounds__(1024) void gru_k(const float* __restrict__ wihT,
    const float* __restrict__ whhT, const float* __restrict__ bhh,
    const float* __restrict__ ai, const float* __restrict__ fpost,
    const float* __restrict__ pwTh, float* __restrict__ out)
{
    float* out_post = out + 1048576;
    float* out_h    = out + 2097152;
    float* out_z    = out + 2228224;
    int b   = blockIdx.x;
    int tid = threadIdx.x;
    __shared__ __align__(16) float h[128];
    __shared__ float gi[384], gh[384];
    __shared__ int idx[32];
    if (tid < 128) h[tid] = 0.f;
    __syncthreads();

    for (int t = 0; t < 64; t++) {
        int n = b * 64 + t;
        if (tid < 384) {
            float a = ai[(size_t)n * 384 + tid];
            if (t > 0) {
#pragma unroll 8
                for (int c = 0; c < 32; c++)
                    a += wihT[(size_t)(c * 32 + idx[c]) * 384 + tid];
            }
            gi[tid] = a;
            float a2 = bhh[tid];
            const float* wc = whhT + tid;            // coalesced column walk
#pragma unroll 8
            for (int k = 0; k < 128; k += 4) {
                float4 hv = *(const float4*)(h + k); // ds_read_b128 broadcast
                a2 += wc[(size_t)k * 384]       * hv.x
                    + wc[(size_t)(k + 1) * 384] * hv.y
                    + wc[(size_t)(k + 2) * 384] * hv.z
                    + wc[(size_t)(k + 3) * 384] * hv.w;
            }
            gh[tid] = a2;
        }
        __syncthreads();                                    // B1
        if (tid < 128) {
            float r  = sigm_f(gi[tid] + gh[tid]);
            float u  = sigm_f(gi[128 + tid] + gh[128 + tid]);
            float nn = tanhf(gi[256 + tid] + r * gh[256 + tid]);
            float hn = (1.f - u) * nn + u * h[tid];
            h[tid] = hn;
            out_h[(size_t)n * 128 + tid] = hn;
        }
        __syncthreads();                                    // B2
        if (tid < 512) {
            // outputs j0 = tid, j1 = tid + 512 (chunks c0 = tid>>5, c0+16)
            float a0 = fpost[(size_t)n * 1024 + tid];
            float a1 = fpost[(size_t)n * 1024 + 512 + tid];
            const float* wc0 = pwTh + tid;           // coalesced column walk
            const float* wc1 = pwTh + 512 + tid;
#pragma unroll 8
            for (int k = 0; k < 128; k += 4) {
                float4 hv = *(const float4*)(h + k); // reused for both outputs
                size_t o0 = (size_t)k * 1024;
                a0 += wc0[o0]        * hv.x + wc0[o0 + 1024] * hv.y
                    + wc0[o0 + 2048] * hv.z + wc0[o0 + 3072] * hv.w;
                a1 += wc1[o0]        * hv.x + wc1[o0 + 1024] * hv.y
                    + wc1[o0 + 2048] * hv.z + wc1[o0 + 3072] * hv.w;
            }
            out_post[(size_t)n * 1024 + tid]       = a0;
            out_post[(size_t)n * 1024 + 512 + tid] = a1;

            // first-max argmax over each 32-lane chunk, in-register butterfly
            float b0 = a0, b1 = a1;
            int i0 = tid & 31, i1 = tid & 31;
#pragma unroll
            for (int m = 16; m >= 1; m >>= 1) {
                float ob0 = __shfl_xor(b0, m);
                int   oi0 = __shfl_xor(i0, m);
                float ob1 = __shfl_xor(b1, m);
                int   oi1 = __shfl_xor(i1, m);
                if (ob0 > b0 || (ob0 == b0 && oi0 < i0)) { b0 = ob0; i0 = oi0; }
                if (ob1 > b1 || (ob1 == b1 && oi1 < i1)) { b1 = ob1; i1 = oi1; }
            }
            out_z[(size_t)n * 1024 + tid]       = ((tid & 31) == i0) ? 1.f : 0.f;
            out_z[(size_t)n * 1024 + 512 + tid] = ((tid & 31) == i1) ? 1.f : 0.f;
            if ((tid & 31) == 0) {
                idx[tid >> 5]        = i0;
                idx[(tid >> 5) + 16] = i1;
            }
        }
        __syncthreads();                                    // B3
    }
}

// ---------------------------------------------------------------------------
extern "C" void kernel_launch(void* const* d_in, const int* in_sizes, int n_in,
                              void* d_out, int out_size, void* d_ws, size_t ws_size,
                              hipStream_t stream)
{
    const float* states  = (const float*)d_in[0];
    const float* actions = (const float*)d_in[1];
    const float* c1w = (const float*)d_in[2];  const float* c1b = (const float*)d_in[3];
    const float* l1g = (const float*)d_in[4];  const float* l1b = (const float*)d_in[5];
    const float* c2w = (const float*)d_in[6];  const float* c2b = (const float*)d_in[7];
    const float* l2g = (const float*)d_in[8];  const float* l2b = (const float*)d_in[9];
    const float* c3w = (const float*)d_in[10]; const float* c3b = (const float*)d_in[11];
    const float* l3g = (const float*)d_in[12]; const float* l3b = (const float*)d_in[13];
    const float* c4w = (const float*)d_in[14]; const float* c4b = (const float*)d_in[15];
    const float* l4g = (const float*)d_in[16]; const float* l4b = (const float*)d_in[17];
    const float* fcw = (const float*)d_in[18]; const float* fcb = (const float*)d_in[19];
    const float* wih = (const float*)d_in[20]; const float* whh = (const float*)d_in[21];
    const float* bih = (const float*)d_in[22]; const float* bhh = (const float*)d_in[23];
    const float* prw = (const float*)d_in[24]; const float* prb = (const float*)d_in[25];
    const float* pw  = (const float*)d_in[26]; const float* pb  = (const float*)d_in[27];

    float* out = (float*)d_out;
    float* ws  = (float*)d_ws;

    // ---- adaptive chunking: largest S whose footprint fits ws_size --------
    // footprint = (S*49152 + fixed 3,325,952) floats
    size_t S = 64;
    {
        const size_t cands[4] = {1024, 512, 256, 128};
        for (int i = 0; i < 4; i++) {
            size_t need = (cands[i] * 49152ull + 3325952ull) * 4ull;
            if (need <= ws_size) { S = cands[i]; break; }
        }
    }
    int C = (int)(1024 / S);

    float* bufA  = ws;                       // S*32768
    float* bufB  = bufA + S * 32768;         // S*16384
    float* feats = bufB + S * 16384;         //   262,144
    float* fpost = feats + 262144;           // 1,048,576
    float* aibuf = fpost + 1048576;          //   393,216
    float* wihT  = aibuf + 393216;           //   393,216
    float* fcwT  = wihT + 393216;            // 1,048,576
    float* whhT  = fcwT + 1048576;           //    49,152
    float* pwTh  = whhT + 49152;             //   131,072

    trfc_k<<<dim3(128, 8), 256, 0, stream>>>(fcw, fcwT);
    tr_whh_k<<<192, 256, 0, stream>>>(whh, whhT);
    tr_pw_k<<<512, 256, 0, stream>>>(pw, pwTh);

    for (int cc = 0; cc < C; cc++) {
        size_t n0 = (size_t)cc * S;
        conv1_k<<<dim3((unsigned)S, 4), 256, 0, stream>>>(states + n0 * 12288, c1w, c1b, bufA);
        ln_fuse_k<<<(unsigned)S, 256, 0, stream>>>(bufA, l1g, l1b, 32768);
        conv2_r<<<(unsigned)S, 256, 0, stream>>>(bufA, c2w, c2b, bufB);
        ln_fuse_k<<<(unsigned)S, 256, 0, stream>>>(bufB, l2g, l2b, 16384);
        conv3_r<<<(unsigned)(S / 2), 256, 0, stream>>>(bufB, c3w, c3b, bufA);
        ln_fuse_k<<<(unsigned)S, 256, 0, stream>>>(bufA, l3g, l3b, 8192);
        conv4_f<<<(unsigned)S, 256, 0, stream>>>(bufA, c4w, c4b, l4g, l4b, bufB);
        fc_k2<<<(unsigned)(S / 8), 256, 0, stream>>>(bufB, fcwT, fcb, feats + n0 * 256);
    }

    fpost_k<<<256, 256, 0, stream>>>(feats, pw, pb, fpost);
    ai_k<<<dim3(1024, 3), 128, 0, stream>>>(actions, wih, bih, aibuf);
    tr_k<<<1536, 256, 0, stream>>>(wih, wihT);

    gru_k<<<16, 1024, 0, stream>>>(wihT, whhT, bhh, aibuf, fpost, pwTh, out);
    prior_k<<<256, 256, 0, stream>>>(out + 2097152, prw, prb, out);
}

// Round 4
// 2546.111 us; speedup vs baseline: 1.2293x; 1.0625x over previous
//
#include <hip/hip_runtime.h>
#include <math.h>

// ---------------------------------------------------------------------------
// RSSM: B=16, T=64 (bt=1024), encoder 3->32->64->128->256 (k4 s2 p1) with
// full-tensor LayerNorm+SiLU per layer, fc 4096->256, GRU(1030->128),
// prior 128->1024, post 384->1024, z = per-32-chunk argmax one-hot.
// All fp32: one flipped argmax = 1.0 error in z -> low precision in the
// logit path is fatal.
// R7 changes (from profile): conv3_r stuck at 642us with Occupancy 11.8%
// (1 block/CU) and VALUBusy 37% -- the 2-samples/block packing halved the
// grid to 512 blocks, and a lone 4-wave block in barrier lockstep can't
// hide ds_read->FMA latency. Now conv3 is 1 sample/block (1024 blocks),
// 8 half-wave groups x 16 oc, acc[16]x2 (32 acc VGPRs), LDS 36.9KB ->
// 4 blocks/CU. Weight reads broadcast within half-wave (2 addrs/wave =
// free 2-way). Inner-loop ratio stays 1 b128 : 8 FMA like conv2.
// ---------------------------------------------------------------------------

__device__ __forceinline__ float silu_f(float t){ return t / (1.f + __expf(-t)); }
__device__ __forceinline__ float sigm_f(float x){ return 1.f / (1.f + expf(-x)); }

// Block-level mean/rstd over m values; each thread contributes (s, s2).
__device__ __forceinline__ void block_stats_256(float s, float s2, int m,
                                                float& mean, float& rstd)
{
    __shared__ float red[8];
#pragma unroll
    for (int off = 32; off > 0; off >>= 1) {
        s  += __shfl_down(s, off);
        s2 += __shfl_down(s2, off);
    }
    int wv = threadIdx.x >> 6;
    if ((threadIdx.x & 63) == 0) { red[wv] = s; red[4 + wv] = s2; }
    __syncthreads();
    if (threadIdx.x == 0) {
        float S  = (red[0] + red[1]) + (red[2] + red[3]);
        float S2 = (red[4] + red[5]) + (red[6] + red[7]);
        float mu = S / m;
        float var = S2 / m - mu * mu;
        red[0] = mu;
        red[1] = rsqrtf(var + 1e-5f);
    }
    __syncthreads();
    mean = red[0]; rstd = red[1];
}

// ---------------- fused LayerNorm+SiLU, one block per sample ---------------
__global__ __launch_bounds__(256) void ln_fuse_k(float* __restrict__ x,
    const float* __restrict__ g, const float* __restrict__ b, int m)
{
    int n = blockIdx.x;
    float* p = x + (size_t)n * m;
    float s = 0.f, s2 = 0.f;
    for (int i = threadIdx.x * 4; i < m; i += 1024) {
        float4 v = *(const float4*)(p + i);
        s  += (v.x + v.y) + (v.z + v.w);
        s2 += (v.x*v.x + v.y*v.y) + (v.z*v.z + v.w*v.w);
    }
    float mean, rstd;
    block_stats_256(s, s2, m, mean, rstd);
    for (int i = threadIdx.x * 4; i < m; i += 1024) {
        float4 v  = *(float4*)(p + i);
        float4 gv = *(const float4*)(g + i);
        float4 bv = *(const float4*)(b + i);
        v.x = silu_f((v.x - mean) * rstd * gv.x + bv.x);
        v.y = silu_f((v.y - mean) * rstd * gv.y + bv.y);
        v.z = silu_f((v.z - mean) * rstd * gv.z + bv.z);
        v.w = silu_f((v.w - mean) * rstd * gv.w + bv.w);
        *(float4*)(p + i) = v;
    }
}

// ------------------------- conv1: 3x64x64 -> 32x32x32 ----------------------
__global__ __launch_bounds__(256) void conv1_k(const float* __restrict__ in,
    const float* __restrict__ w, const float* __restrict__ bias, float* __restrict__ out)
{
    int n  = blockIdx.x;                 // chunk-local sample
    int yq = blockIdx.y;                 // 4 y-quarters
    int tx = threadIdx.x & 31;
    int ty = threadIdx.x >> 5;           // 0..7
    int y  = yq * 8 + ty;                // 0..31
    const float* ip = in + (size_t)n * 12288;

    float okf[16]; int offs[16];
#pragma unroll
    for (int ky = 0; ky < 4; ky++) {
        int yy = 2 * y - 1 + ky;
        bool yok = ((unsigned)yy < 64u);
#pragma unroll
        for (int kx = 0; kx < 4; kx++) {
            int xx = 2 * tx - 1 + kx;
            bool ok = yok && ((unsigned)xx < 64u);
            okf[ky*4+kx]  = ok ? 1.f : 0.f;
            offs[ky*4+kx] = ok ? yy * 64 + xx : 0;
        }
    }
    float iv[48];
#pragma unroll
    for (int c = 0; c < 3; c++)
#pragma unroll
        for (int q = 0; q < 16; q++)
            iv[c*16+q] = ip[c*4096 + offs[q]] * okf[q];

    float* op = out + (size_t)n * 32768 + y * 32 + tx;
#pragma unroll 4
    for (int oc = 0; oc < 32; oc++) {           // oc uniform -> weights s_load
        float acc = bias[oc];
        const float* wp = w + oc * 48;
#pragma unroll
        for (int q = 0; q < 48; q++) acc += iv[q] * wp[q];
        op[oc * 1024] = acc;
    }
}

// ------- conv2: 32x32x32 -> 64x16x16 -------------------------------------
// Block = 1 sample, 256 thr. Wave pair -> oc half (32 oc); 128 pos-slots,
// thread = (y0,x) and (y0+8,x). LDS: [4ch: 4 zero + 1024 rot-swizzled] +
// [4ch x 64oc x 16 weights]. Inner: iv 32 b32 + weights broadcast b128.
__global__ __launch_bounds__(256) void conv2_r(const float* __restrict__ in,
    const float* __restrict__ w, const float* __restrict__ bias, float* __restrict__ out)
{
    __shared__ __align__(16) float lds[8208];     // 4*1028 input + 4096 wt
    int n  = blockIdx.x;
    int tid = threadIdx.x;
    int wv  = tid >> 6;
    int g   = wv >> 1;                            // oc half 0/1
    int s   = ((wv & 1) << 6) | (tid & 63);       // 0..127
    int x   = s & 15, y0 = s >> 4;                // x 0..15, y0 0..7
    const float* ip = in + (size_t)n * 32768;

    int offs[2][16];
#pragma unroll
    for (int p = 0; p < 2; p++) {
        int y = y0 + 8 * p;
#pragma unroll
        for (int ky = 0; ky < 4; ky++) {
            int yi = 2 * y - 1 + ky;
#pragma unroll
            for (int kx = 0; kx < 4; kx++) {
                int xi = 2 * x - 1 + kx;
                bool ok = ((unsigned)yi < 32u) && ((unsigned)xi < 32u);
                int rot = ((xi >> 2) + (yi & 7)) & 7;
                int foff = yi * 32 + rot * 4 + (xi & 3);
                offs[p][ky*4+kx] = ok ? (4 + foff) * 4 : 0;   // bytes; 0 = zero slot
            }
        }
    }
    if (tid < 16) lds[(tid >> 2) * 1028 + (tid & 3)] = 0.f;   // zero slots

    float acc0[32], acc1[32];
#pragma unroll
    for (int i = 0; i < 32; i++) { float bv = bias[g*32 + i]; acc0[i] = bv; acc1[i] = bv; }

#pragma unroll 1
    for (int ch = 0; ch < 8; ch++) {              // 8 chunks x 4 channels
        __syncthreads();
        {   // stage input: 4 ch x 1024 fl, rotated rows
            const float4* gs = (const float4*)(ip + (ch << 12));
#pragma unroll
            for (int k = 0; k < 4; k++) {
                int gid = tid + (k << 8);         // 0..1023 f4s
                int cc = gid >> 8, r = (gid >> 3) & 31, s4 = gid & 7;
                int rs = (s4 + (r & 7)) & 7;
                *(float4*)&lds[cc*1028 + 4 + r*32 + rs*4] = gs[gid];
            }
            // stage weights: 4 ch x 64 oc x 16
            int oc = tid >> 2, i4 = tid & 3;
            const float* wg = w + (size_t)oc * 512 + (ch << 6) + i4 * 4;
#pragma unroll
            for (int cc = 0; cc < 4; cc++)
                *(float4*)&lds[4112 + cc*1024 + oc*16 + i4*4] =
                    *(const float4*)(wg + cc * 16);
        }
        __syncthreads();
#pragma unroll 1
        for (int cc = 0; cc < 4; cc++) {
            const char* cb = (const char*)lds + cc * 4112;
            float iv0[16], iv1[16];
#pragma unroll
            for (int q = 0; q < 16; q++) {
                iv0[q] = *(const float*)(cb + offs[0][q]);
                iv1[q] = *(const float*)(cb + offs[1][q]);
            }
            const float* wb = &lds[4112 + cc*1024 + g*512];   // wave-uniform base
#pragma unroll
            for (int o = 0; o < 32; o++) {
                float wt[16];
                *(float4*)&wt[0]  = *(const float4*)(wb + o*16);
                *(float4*)&wt[4]  = *(const float4*)(wb + o*16 + 4);
                *(float4*)&wt[8]  = *(const float4*)(wb + o*16 + 8);
                *(float4*)&wt[12] = *(const float4*)(wb + o*16 + 12);
#pragma unroll
                for (int q = 0; q < 16; q++) {
                    acc0[o] = fmaf(iv0[q], wt[q], acc0[o]);
                    acc1[o] = fmaf(iv1[q], wt[q], acc1[o]);
                }
            }
        }
    }
    float* op = out + (size_t)n * 16384;
#pragma unroll
    for (int o = 0; o < 32; o++) {
        op[(g*32 + o) * 256 + y0*16 + x]       = acc0[o];
        op[(g*32 + o) * 256 + (y0+8)*16 + x]   = acc1[o];
    }
}

// ------- conv3: 64x16x16 -> 128x8x8, 1 sample/block, 8 groups x 16 oc ------
// 256 thr = 8 half-wave groups; group g -> oc[16g..16g+16); lane slot 0..31
// covers positions {slot, slot+32}. Weight reads broadcast within half-wave
// (2 distinct addrs/wave = free 2-way). 16 chunks x 4 ch; LDS 36.9KB ->
// 4 blocks/CU for latency hiding (R6 had 1 block/CU, 37% VALU).
__global__ __launch_bounds__(256) void conv3_r(const float* __restrict__ in,
    const float* __restrict__ w, const float* __restrict__ bias, float* __restrict__ out)
{
    __shared__ __align__(16) float lds[9232];    // 4*260 input + 8192 wt
    int n   = blockIdx.x;
    int tid = threadIdx.x;
    int g   = tid >> 5;                  // 0..7 -> oc group (16 oc)
    int slot= tid & 31;
    int x   = slot & 7, y0 = slot >> 3;  // x 0..7, y0 0..3

    int offs[2][16];
#pragma unroll
    for (int p = 0; p < 2; p++) {
        int y = y0 + 4 * p;
#pragma unroll
        for (int ky = 0; ky < 4; ky++) {
            int yi = 2 * y - 1 + ky;
#pragma unroll
            for (int kx = 0; kx < 4; kx++) {
                int xi = 2 * x - 1 + kx;
                bool ok = ((unsigned)yi < 16u) && ((unsigned)xi < 16u);
                int rot = ((xi >> 2) + (yi & 3)) & 3;
                int foff = yi * 16 + rot * 4 + (xi & 3);
                offs[p][ky*4+kx] = ok ? (4 + foff) * 4 : 0;   // bytes; 0 = zero slot
            }
        }
    }
    if (tid < 16) lds[(tid >> 2) * 260 + (tid & 3)] = 0.f;    // zero slots

    float acc0[16], acc1[16];
#pragma unroll
    for (int i = 0; i < 16; i++) { float bv = bias[g*16 + i]; acc0[i] = bv; acc1[i] = bv; }

    const float* ip = in + (size_t)n * 16384;
#pragma unroll 1
    for (int ch = 0; ch < 16; ch++) {             // 16 chunks x 4 channels
        __syncthreads();
        {   // stage input: 4 ch x 256 fl, rotated rows (1 f4/thread)
            const float4* gs = (const float4*)(ip + (ch << 10));
            int cc = tid >> 6, r = (tid >> 2) & 15, s4 = tid & 3;
            int rs = (s4 + (r & 3)) & 3;
            *(float4*)&lds[cc*260 + 4 + r*16 + rs*4] = gs[tid];
            // stage weights: 4 ch x 128 oc x 16 (8 f4/thread)
            int oc = tid >> 1, h = tid & 1;
            const float* wg = w + (size_t)oc * 1024 + (ch << 6) + h * 8;
#pragma unroll
            for (int c2 = 0; c2 < 4; c2++) {
                *(float4*)&lds[1040 + c2*2048 + oc*16 + h*8]     = *(const float4*)(wg + c2*16);
                *(float4*)&lds[1040 + c2*2048 + oc*16 + h*8 + 4] = *(const float4*)(wg + c2*16 + 4);
            }
        }
        __syncthreads();
#pragma unroll 1
        for (int cc = 0; cc < 4; cc++) {
            const char* cb = (const char*)lds + cc * 1040;
            float iv0[16], iv1[16];
#pragma unroll
            for (int q = 0; q < 16; q++) {
                iv0[q] = *(const float*)(cb + offs[0][q]);
                iv1[q] = *(const float*)(cb + offs[1][q]);
            }
            const float* wb = &lds[1040 + cc*2048 + g*256];   // half-wave-uniform
#pragma unroll
            for (int o = 0; o < 16; o++) {
                float wt[16];
                *(float4*)&wt[0]  = *(const float4*)(wb + o*16);
                *(float4*)&wt[4]  = *(const float4*)(wb + o*16 + 4);
                *(float4*)&wt[8]  = *(const float4*)(wb + o*16 + 8);
                *(float4*)&wt[12] = *(const float4*)(wb + o*16 + 12);
#pragma unroll
                for (int q = 0; q < 16; q++) {
                    acc0[o] = fmaf(iv0[q], wt[q], acc0[o]);
                    acc1[o] = fmaf(iv1[q], wt[q], acc1[o]);
                }
            }
        }
    }
    float* op = out + (size_t)n * 8192;
#pragma unroll
    for (int o = 0; o < 16; o++) {
        op[(g*16 + o) * 64 + slot]      = acc0[o];
        op[(g*16 + o) * 64 + slot + 32] = acc1[o];
    }
}

// ----------------- conv4 + LN4 + SiLU: 128x8x8 -> 256x4x4 ------------------
__global__ __launch_bounds__(256) void conv4_f(const float* __restrict__ in,
    const float* __restrict__ w, const float* __restrict__ bias,
    const float* __restrict__ g, const float* __restrict__ bet, float* __restrict__ out)
{
    int n  = blockIdx.x;
    int oc = threadIdx.x;                 // 0..255
    const float* ip = in + (size_t)n * 8192;
    const float* wr = w + (size_t)oc * 2048;

    float acc[16];
#pragma unroll
    for (int s = 0; s < 16; s++) acc[s] = bias[oc];

    for (int c = 0; c < 128; c++) {
        const float* ic = ip + c * 64;     // uniform base -> s_load, CSE'd
        const float* wc = wr + c * 16;
        float wf[16];
#pragma unroll
        for (int q = 0; q < 16; q += 4) {
            float4 v = *(const float4*)(wc + q);
            wf[q] = v.x; wf[q+1] = v.y; wf[q+2] = v.z; wf[q+3] = v.w;
        }
#pragma unroll
        for (int y = 0; y < 4; y++)
#pragma unroll
        for (int x = 0; x < 4; x++) {
            float a = acc[y * 4 + x];
#pragma unroll
            for (int ky = 0; ky < 4; ky++) {
                int yy = 2 * y - 1 + ky;
                if (yy < 0 || yy > 7) continue;      // folds at compile time
#pragma unroll
                for (int kx = 0; kx < 4; kx++) {
                    int xx = 2 * x - 1 + kx;
                    if (xx < 0 || xx > 7) continue;
                    a += wf[ky * 4 + kx] * ic[yy * 8 + xx];
                }
            }
            acc[y * 4 + x] = a;
        }
    }
    float s = 0.f, s2 = 0.f;
#pragma unroll
    for (int q = 0; q < 16; q++) { s += acc[q]; s2 += acc[q] * acc[q]; }
    float mean, rstd;
    block_stats_256(s, s2, 4096, mean, rstd);

    float* op = out + (size_t)n * 4096;
#pragma unroll
    for (int q = 0; q < 16; q++) {
        int flat = oc * 16 + q;
        float v = (acc[q] - mean) * rstd * g[flat] + bet[flat];
        op[flat] = silu_f(v);
    }
}

// -------- transpose fc_w [256][4096] -> fcwT [4096][256] (LDS-tiled) -------
__global__ __launch_bounds__(256) void trfc_k(const float* __restrict__ w,
                                              float* __restrict__ wt)
{
    __shared__ float t[32][33];
    int bk = blockIdx.x * 32;             // k dim (4096)
    int bj = blockIdx.y * 32;             // j dim (256)
    int lx = threadIdx.x & 31, ly = threadIdx.x >> 5;   // 32 x 8
#pragma unroll
    for (int s = 0; s < 4; s++)
        t[ly + 8*s][lx] = w[(size_t)(bj + ly + 8*s) * 4096 + bk + lx];
    __syncthreads();
#pragma unroll
    for (int s = 0; s < 4; s++)
        wt[(size_t)(bk + ly + 8*s) * 256 + bj + lx] = t[lx][ly + 8*s];
}

// ---------------- fc: [S,4096] @ wT[4096][256], coalesced ------------------
__global__ __launch_bounds__(256) void fc_k2(const float* __restrict__ a,
    const float* __restrict__ wT, const float* __restrict__ bias, float* __restrict__ o)
{
    int n0 = blockIdx.x * 8;              // chunk-local rows
    int j  = threadIdx.x;
    float acc[8];
#pragma unroll
    for (int r = 0; r < 8; r++) acc[r] = 0.f;
    for (int k = 0; k < 4096; k += 4) {
        float wv0 = wT[(size_t)k * 256 + j];
        float wv1 = wT[(size_t)(k+1) * 256 + j];
        float wv2 = wT[(size_t)(k+2) * 256 + j];
        float wv3 = wT[(size_t)(k+3) * 256 + j];
#pragma unroll
        for (int r = 0; r < 8; r++) {
            const float* ar = a + (size_t)(n0 + r) * 4096 + k;   // uniform -> s_load x4
            acc[r] += wv0*ar[0] + wv1*ar[1] + wv2*ar[2] + wv3*ar[3];
        }
    }
    float bj = bias[j];
#pragma unroll
    for (int r = 0; r < 8; r++) o[(size_t)(n0 + r) * 256 + j] = acc[r] + bj;
}

// ----------- Fpost[n,j] = post_b[j] + feats[n,:] @ post_w[j,128:384] -------
__global__ __launch_bounds__(256) void fpost_k(const float* __restrict__ f,
    const float* __restrict__ w, const float* __restrict__ bias, float* __restrict__ o)
{
    int n0 = blockIdx.x * 4;
    int tid = threadIdx.x;
    float acc[4][4];
#pragma unroll
    for (int r = 0; r < 4; r++)
#pragma unroll
        for (int jj = 0; jj < 4; jj++) acc[r][jj] = 0.f;
    for (int k = 0; k < 256; k += 4) {
        float4 wv[4];
#pragma unroll
        for (int jj = 0; jj < 4; jj++)
            wv[jj] = *(const float4*)(w + (size_t)(tid + jj * 256) * 384 + 128 + k);
#pragma unroll
        for (int r = 0; r < 4; r++) {
            const float* fr = f + (size_t)(n0 + r) * 256 + k;    // uniform
            float a0 = fr[0], a1 = fr[1], a2 = fr[2], a3 = fr[3];
#pragma unroll
            for (int jj = 0; jj < 4; jj++)
                acc[r][jj] += wv[jj].x*a0 + wv[jj].y*a1 + wv[jj].z*a2 + wv[jj].w*a3;
        }
    }
#pragma unroll
    for (int jj = 0; jj < 4; jj++) {
        float bj = bias[tid + jj * 256];
#pragma unroll
        for (int r = 0; r < 4; r++)
            o[(size_t)(n0 + r) * 1024 + tid + jj * 256] = acc[r][jj] + bj;
    }
}

// ----------- prior[n,j] = prior_b[j] + h[n,:] @ prior_w[j,:] ---------------
__global__ __launch_bounds__(256) void prior_k(const float* __restrict__ h,
    const float* __restrict__ w, const float* __restrict__ bias, float* __restrict__ o)
{
    int n0 = blockIdx.x * 4;
    int tid = threadIdx.x;
    float acc[4][4];
#pragma unroll
    for (int r = 0; r < 4; r++)
#pragma unroll
        for (int jj = 0; jj < 4; jj++) acc[r][jj] = 0.f;
    for (int k = 0; k < 128; k += 4) {
        float4 wv[4];
#pragma unroll
        for (int jj = 0; jj < 4; jj++)
            wv[jj] = *(const float4*)(w + (size_t)(tid + jj * 256) * 128 + k);
#pragma unroll
        for (int r = 0; r < 4; r++) {
            const float* hr = h + (size_t)(n0 + r) * 128 + k;    // uniform
            float a0 = hr[0], a1 = hr[1], a2 = hr[2], a3 = hr[3];
#pragma unroll
            for (int jj = 0; jj < 4; jj++)
                acc[r][jj] += wv[jj].x*a0 + wv[jj].y*a1 + wv[jj].z*a2 + wv[jj].w*a3;
        }
    }
#pragma unroll
    for (int jj = 0; jj < 4; jj++) {
        float bj = bias[tid + jj * 256];
#pragma unroll
        for (int r = 0; r < 4; r++)
            o[(size_t)(n0 + r) * 1024 + tid + jj * 256] = acc[r][jj] + bj;
    }
}

// ----------- Ai[n,j] = bih[j] + actions[n,:] @ wih[j,1024:1030] ------------
__global__ __launch_bounds__(128) void ai_k(const float* __restrict__ act,
    const float* __restrict__ wih, const float* __restrict__ bih, float* __restrict__ o)
{
    int n = blockIdx.x;
    int j = blockIdx.y * 128 + threadIdx.x;     // 0..383
    const float* ar = act + (size_t)n * 6;       // uniform
    const float* wr = wih + (size_t)j * 1030 + 1024;
    float acc = bih[j];
#pragma unroll
    for (int k = 0; k < 6; k++) acc += ar[k] * wr[k];
    o[(size_t)n * 384 + j] = acc;
}

// ----------- wihT[k,j] = wih[j,k]  (z-part only, k<1024) -------------------
__global__ __launch_bounds__(256) void tr_k(const float* __restrict__ wih,
                                            float* __restrict__ wt)
{
    int g = blockIdx.x * 256 + threadIdx.x;      // 0..393215
    int k = g / 384;
    int j = g - k * 384;
    wt[g] = wih[(size_t)j * 1030 + k];
}

// ----------- whhT[k,j] = whh[j,k]  ([128][384] from [384][128]) ------------
__global__ __launch_bounds__(256) void tr_whh_k(const float* __restrict__ whh,
                                                float* __restrict__ wt)
{
    int g = blockIdx.x * 256 + threadIdx.x;      // 0..49151
    int k = g / 384;
    int j = g - k * 384;
    wt[g] = whh[(size_t)j * 128 + k];
}

// ----------- pwTh[k,j] = post_w[j,k] (h-cols only, k<128) ------------------
__global__ __launch_bounds__(256) void tr_pw_k(const float* __restrict__ pw,
                                               float* __restrict__ wt)
{
    int g = blockIdx.x * 256 + threadIdx.x;      // 0..131071
    int k = g >> 10;
    int j = g & 1023;
    wt[g] = pw[(size_t)j * 384 + k];
}

// ------------------------- GRU recurrence (1 block / sample) ---------------
// R4: transposed weights (whhT [128][384], pwTh [128][1024]) -> every weight
// load is wave-coalesced; h read as float4 from LDS; post stage 2 outputs/
// thread; argmax as in-register 32-lane shfl_xor butterfly.
__global__ __launch_bounds__(1024) void gru_k(const float* __restrict__ wihT,
    const float* __restrict__ whhT, const float* __restrict__ bhh,
    const float* __restrict__ ai, const float* __restrict__ fpost,
    const float* __restrict__ pwTh, float* __restrict__ out)
{
    float* out_post = out + 1048576;
    float* out_h    = out + 2097152;
    float* out_z    = out + 2228224;
    int b   = blockIdx.x;
    int tid = threadIdx.x;
    __shared__ __align__(16) float h[128];
    __shared__ float gi[384], gh[384];
    __shared__ int idx[32];
    if (tid < 128) h[tid] = 0.f;
    __syncthreads();

    for (int t = 0; t < 64; t++) {
        int n = b * 64 + t;
        if (tid < 384) {
            float a = ai[(size_t)n * 384 + tid];
            if (t > 0) {
#pragma unroll 8
                for (int c = 0; c < 32; c++)
                    a += wihT[(size_t)(c * 32 + idx[c]) * 384 + tid];
            }
            gi[tid] = a;
            float a2 = bhh[tid];
            const float* wc = whhT + tid;            // coalesced column walk
#pragma unroll 8
            for (int k = 0; k < 128; k += 4) {
                float4 hv = *(const float4*)(h + k); // ds_read_b128 broadcast
                a2 += wc[(size_t)k * 384]       * hv.x
                    + wc[(size_t)(k + 1) * 384] * hv.y
                    + wc[(size_t)(k + 2) * 384] * hv.z
                    + wc[(size_t)(k + 3) * 384] * hv.w;
            }
            gh[tid] = a2;
        }
        __syncthreads();                                    // B1
        if (tid < 128) {
            float r  = sigm_f(gi[tid] + gh[tid]);
            float u  = sigm_f(gi[128 + tid] + gh[128 + tid]);
            float nn = tanhf(gi[256 + tid] + r * gh[256 + tid]);
            float hn = (1.f - u) * nn + u * h[tid];
            h[tid] = hn;
            out_h[(size_t)n * 128 + tid] = hn;
        }
        __syncthreads();                                    // B2
        if (tid < 512) {
            // outputs j0 = tid, j1 = tid + 512 (chunks c0 = tid>>5, c0+16)
            float a0 = fpost[(size_t)n * 1024 + tid];
            float a1 = fpost[(size_t)n * 1024 + 512 + tid];
            const float* wc0 = pwTh + tid;           // coalesced column walk
            const float* wc1 = pwTh + 512 + tid;
#pragma unroll 8
            for (int k = 0; k < 128; k += 4) {
                float4 hv = *(const float4*)(h + k); // reused for both outputs
                size_t o0 = (size_t)k * 1024;
                a0 += wc0[o0]        * hv.x + wc0[o0 + 1024] * hv.y
                    + wc0[o0 + 2048] * hv.z + wc0[o0 + 3072] * hv.w;
                a1 += wc1[o0]        * hv.x + wc1[o0 + 1024] * hv.y
                    + wc1[o0 + 2048] * hv.z + wc1[o0 + 3072] * hv.w;
            }
            out_post[(size_t)n * 1024 + tid]       = a0;
            out_post[(size_t)n * 1024 + 512 + tid] = a1;

            // first-max argmax over each 32-lane chunk, in-register butterfly
            float b0 = a0, b1 = a1;
            int i0 = tid & 31, i1 = tid & 31;
#pragma unroll
            for (int m = 16; m >= 1; m >>= 1) {
                float ob0 = __shfl_xor(b0, m);
                int   oi0 = __shfl_xor(i0, m);
                float ob1 = __shfl_xor(b1, m);
                int   oi1 = __shfl_xor(i1, m);
                if (ob0 > b0 || (ob0 == b0 && oi0 < i0)) { b0 = ob0; i0 = oi0; }
                if (ob1 > b1 || (ob1 == b1 && oi1 < i1)) { b1 = ob1; i1 = oi1; }
            }
            out_z[(size_t)n * 1024 + tid]       = ((tid & 31) == i0) ? 1.f : 0.f;
            out_z[(size_t)n * 1024 + 512 + tid] = ((tid & 31) == i1) ? 1.f : 0.f;
            if ((tid & 31) == 0) {
                idx[tid >> 5]        = i0;
                idx[(tid >> 5) + 16] = i1;
            }
        }
        __syncthreads();                                    // B3
    }
}

// ---------------------------------------------------------------------------
extern "C" void kernel_launch(void* const* d_in, const int* in_sizes, int n_in,
                              void* d_out, int out_size, void* d_ws, size_t ws_size,
                              hipStream_t stream)
{
    const float* states  = (const float*)d_in[0];
    const float* actions = (const float*)d_in[1];
    const float* c1w = (const float*)d_in[2];  const float* c1b = (const float*)d_in[3];
    const float* l1g = (const float*)d_in[4];  const float* l1b = (const float*)d_in[5];
    const float* c2w = (const float*)d_in[6];  const float* c2b = (const float*)d_in[7];
    const float* l2g = (const float*)d_in[8];  const float* l2b = (const float*)d_in[9];
    const float* c3w = (const float*)d_in[10]; const float* c3b = (const float*)d_in[11];
    const float* l3g = (const float*)d_in[12]; const float* l3b = (const float*)d_in[13];
    const float* c4w = (const float*)d_in[14]; const float* c4b = (const float*)d_in[15];
    const float* l4g = (const float*)d_in[16]; const float* l4b = (const float*)d_in[17];
    const float* fcw = (const float*)d_in[18]; const float* fcb = (const float*)d_in[19];
    const float* wih = (const float*)d_in[20]; const float* whh = (const float*)d_in[21];
    const float* bih = (const float*)d_in[22]; const float* bhh = (const float*)d_in[23];
    const float* prw = (const float*)d_in[24]; const float* prb = (const float*)d_in[25];
    const float* pw  = (const float*)d_in[26]; const float* pb  = (const float*)d_in[27];

    float* out = (float*)d_out;
    float* ws  = (float*)d_ws;

    // ---- adaptive chunking: largest S whose footprint fits ws_size --------
    // footprint = (S*49152 + fixed 3,325,952) floats
    size_t S = 64;
    {
        const size_t cands[4] = {1024, 512, 256, 128};
        for (int i = 0; i < 4; i++) {
            size_t need = (cands[i] * 49152ull + 3325952ull) * 4ull;
            if (need <= ws_size) { S = cands[i]; break; }
        }
    }
    int C = (int)(1024 / S);

    float* bufA  = ws;                       // S*32768
    float* bufB  = bufA + S * 32768;         // S*16384
    float* feats = bufB + S * 16384;         //   262,144
    float* fpost = feats + 262144;           // 1,048,576
    float* aibuf = fpost + 1048576;          //   393,216
    float* wihT  = aibuf + 393216;           //   393,216
    float* fcwT  = wihT + 393216;            // 1,048,576
    float* whhT  = fcwT + 1048576;           //    49,152
    float* pwTh  = whhT + 49152;             //   131,072

    trfc_k<<<dim3(128, 8), 256, 0, stream>>>(fcw, fcwT);
    tr_whh_k<<<192, 256, 0, stream>>>(whh, whhT);
    tr_pw_k<<<512, 256, 0, stream>>>(pw, pwTh);

    for (int cc = 0; cc < C; cc++) {
        size_t n0 = (size_t)cc * S;
        conv1_k<<<dim3((unsigned)S, 4), 256, 0, stream>>>(states + n0 * 12288, c1w, c1b, bufA);
        ln_fuse_k<<<(unsigned)S, 256, 0, stream>>>(bufA, l1g, l1b, 32768);
        conv2_r<<<(unsigned)S, 256, 0, stream>>>(bufA, c2w, c2b, bufB);
        ln_fuse_k<<<(unsigned)S, 256, 0, stream>>>(bufB, l2g, l2b, 16384);
        conv3_r<<<(unsigned)S, 256, 0, stream>>>(bufB, c3w, c3b, bufA);
        ln_fuse_k<<<(unsigned)S, 256, 0, stream>>>(bufA, l3g, l3b, 8192);
        conv4_f<<<(unsigned)S, 256, 0, stream>>>(bufA, c4w, c4b, l4g, l4b, bufB);
        fc_k2<<<(unsigned)(S / 8), 256, 0, stream>>>(bufB, fcwT, fcb, feats + n0 * 256);
    }

    fpost_k<<<256, 256, 0, stream>>>(feats, pw, pb, fpost);
    ai_k<<<dim3(1024, 3), 128, 0, stream>>>(actions, wih, bih, aibuf);
    tr_k<<<1536, 256, 0, stream>>>(wih, wihT);

    gru_k<<<16, 1024, 0, stream>>>(wihT, whhT, bhh, aibuf, fpost, pwTh, out);
    prior_k<<<256, 256, 0, stream>>>(out + 2097152, prw, prb, out);
}

// Round 5
// 2511.810 us; speedup vs baseline: 1.2461x; 1.0137x over previous
//
#include <hip/hip_runtime.h>
#include <math.h>

// ---------------------------------------------------------------------------
// RSSM: B=16, T=64 (bt=1024), encoder 3->32->64->128->256 (k4 s2 p1) with
// full-tensor LayerNorm+SiLU per layer, fc 4096->256, GRU(1030->128),
// prior 128->1024, post 384->1024, z = per-32-chunk argmax one-hot.
// All fp32: one flipped argmax = 1.0 error in z -> low precision in the
// logit path is fatal.
// R8 changes (from profile): gru_k 607us at VALUBusy 1.9% / occupancy 3% --
// pure load-latency. Weight matvecs were 128 SCALAR L2 loads per output
// (stride 4KB/1.5KB between k) batched ~8-16 deep by a VGPR=60 budget ->
// ~16 dependent L2 round-trips per phase per step. Now whh and post_w(h)
// are packed k4-major as float4 (wV[k4][j][0:4] = w[j][4k4+c]): lane j
// loads one coalesced float4 per k4 -> 32 loads instead of 128, unroll-8
// batches, __launch_bounds__(1024) frees VGPRs for in-flight loads.
// ---------------------------------------------------------------------------

__device__ __forceinline__ float silu_f(float t){ return t / (1.f + __expf(-t)); }
__device__ __forceinline__ float sigm_f(float x){ return 1.f / (1.f + expf(-x)); }

// Block-level mean/rstd over m values; each thread contributes (s, s2).
__device__ __forceinline__ void block_stats_256(float s, float s2, int m,
                                                float& mean, float& rstd)
{
    __shared__ float red[8];
#pragma unroll
    for (int off = 32; off > 0; off >>= 1) {
        s  += __shfl_down(s, off);
        s2 += __shfl_down(s2, off);
    }
    int wv = threadIdx.x >> 6;
    if ((threadIdx.x & 63) == 0) { red[wv] = s; red[4 + wv] = s2; }
    __syncthreads();
    if (threadIdx.x == 0) {
        float S  = (red[0] + red[1]) + (red[2] + red[3]);
        float S2 = (red[4] + red[5]) + (red[6] + red[7]);
        float mu = S / m;
        float var = S2 / m - mu * mu;
        red[0] = mu;
        red[1] = rsqrtf(var + 1e-5f);
    }
    __syncthreads();
    mean = red[0]; rstd = red[1];
}

// ---------------- fused LayerNorm+SiLU, one block per sample ---------------
__global__ __launch_bounds__(256) void ln_fuse_k(float* __restrict__ x,
    const float* __restrict__ g, const float* __restrict__ b, int m)
{
    int n = blockIdx.x;
    float* p = x + (size_t)n * m;
    float s = 0.f, s2 = 0.f;
    for (int i = threadIdx.x * 4; i < m; i += 1024) {
        float4 v = *(const float4*)(p + i);
        s  += (v.x + v.y) + (v.z + v.w);
        s2 += (v.x*v.x + v.y*v.y) + (v.z*v.z + v.w*v.w);
    }
    float mean, rstd;
    block_stats_256(s, s2, m, mean, rstd);
    for (int i = threadIdx.x * 4; i < m; i += 1024) {
        float4 v  = *(float4*)(p + i);
        float4 gv = *(const float4*)(g + i);
        float4 bv = *(const float4*)(b + i);
        v.x = silu_f((v.x - mean) * rstd * gv.x + bv.x);
        v.y = silu_f((v.y - mean) * rstd * gv.y + bv.y);
        v.z = silu_f((v.z - mean) * rstd * gv.z + bv.z);
        v.w = silu_f((v.w - mean) * rstd * gv.w + bv.w);
        *(float4*)(p + i) = v;
    }
}

// ------------------------- conv1: 3x64x64 -> 32x32x32 ----------------------
__global__ __launch_bounds__(256) void conv1_k(const float* __restrict__ in,
    const float* __restrict__ w, const float* __restrict__ bias, float* __restrict__ out)
{
    int n  = blockIdx.x;                 // chunk-local sample
    int yq = blockIdx.y;                 // 4 y-quarters
    int tx = threadIdx.x & 31;
    int ty = threadIdx.x >> 5;           // 0..7
    int y  = yq * 8 + ty;                // 0..31
    const float* ip = in + (size_t)n * 12288;

    float okf[16]; int offs[16];
#pragma unroll
    for (int ky = 0; ky < 4; ky++) {
        int yy = 2 * y - 1 + ky;
        bool yok = ((unsigned)yy < 64u);
#pragma unroll
        for (int kx = 0; kx < 4; kx++) {
            int xx = 2 * tx - 1 + kx;
            bool ok = yok && ((unsigned)xx < 64u);
            okf[ky*4+kx]  = ok ? 1.f : 0.f;
            offs[ky*4+kx] = ok ? yy * 64 + xx : 0;
        }
    }
    float iv[48];
#pragma unroll
    for (int c = 0; c < 3; c++)
#pragma unroll
        for (int q = 0; q < 16; q++)
            iv[c*16+q] = ip[c*4096 + offs[q]] * okf[q];

    float* op = out + (size_t)n * 32768 + y * 32 + tx;
#pragma unroll 4
    for (int oc = 0; oc < 32; oc++) {           // oc uniform -> weights s_load
        float acc = bias[oc];
        const float* wp = w + oc * 48;
#pragma unroll
        for (int q = 0; q < 48; q++) acc += iv[q] * wp[q];
        op[oc * 1024] = acc;
    }
}

// ------- conv2: 32x32x32 -> 64x16x16 -------------------------------------
// Block = 1 sample, 256 thr. Wave pair -> oc half (32 oc); 128 pos-slots,
// thread = (y0,x) and (y0+8,x). LDS: [4ch: 4 zero + 1024 rot-swizzled] +
// [4ch x 64oc x 16 weights]. Inner: iv 32 b32 + weights broadcast b128.
__global__ __launch_bounds__(256) void conv2_r(const float* __restrict__ in,
    const float* __restrict__ w, const float* __restrict__ bias, float* __restrict__ out)
{
    __shared__ __align__(16) float lds[8208];     // 4*1028 input + 4096 wt
    int n  = blockIdx.x;
    int tid = threadIdx.x;
    int wv  = tid >> 6;
    int g   = wv >> 1;                            // oc half 0/1
    int s   = ((wv & 1) << 6) | (tid & 63);       // 0..127
    int x   = s & 15, y0 = s >> 4;                // x 0..15, y0 0..7
    const float* ip = in + (size_t)n * 32768;

    int offs[2][16];
#pragma unroll
    for (int p = 0; p < 2; p++) {
        int y = y0 + 8 * p;
#pragma unroll
        for (int ky = 0; ky < 4; ky++) {
            int yi = 2 * y - 1 + ky;
#pragma unroll
            for (int kx = 0; kx < 4; kx++) {
                int xi = 2 * x - 1 + kx;
                bool ok = ((unsigned)yi < 32u) && ((unsigned)xi < 32u);
                int rot = ((xi >> 2) + (yi & 7)) & 7;
                int foff = yi * 32 + rot * 4 + (xi & 3);
                offs[p][ky*4+kx] = ok ? (4 + foff) * 4 : 0;   // bytes; 0 = zero slot
            }
        }
    }
    if (tid < 16) lds[(tid >> 2) * 1028 + (tid & 3)] = 0.f;   // zero slots

    float acc0[32], acc1[32];
#pragma unroll
    for (int i = 0; i < 32; i++) { float bv = bias[g*32 + i]; acc0[i] = bv; acc1[i] = bv; }

#pragma unroll 1
    for (int ch = 0; ch < 8; ch++) {              // 8 chunks x 4 channels
        __syncthreads();
        {   // stage input: 4 ch x 1024 fl, rotated rows
            const float4* gs = (const float4*)(ip + (ch << 12));
#pragma unroll
            for (int k = 0; k < 4; k++) {
                int gid = tid + (k << 8);         // 0..1023 f4s
                int cc = gid >> 8, r = (gid >> 3) & 31, s4 = gid & 7;
                int rs = (s4 + (r & 7)) & 7;
                *(float4*)&lds[cc*1028 + 4 + r*32 + rs*4] = gs[gid];
            }
            // stage weights: 4 ch x 64 oc x 16
            int oc = tid >> 2, i4 = tid & 3;
            const float* wg = w + (size_t)oc * 512 + (ch << 6) + i4 * 4;
#pragma unroll
            for (int cc = 0; cc < 4; cc++)
                *(float4*)&lds[4112 + cc*1024 + oc*16 + i4*4] =
                    *(const float4*)(wg + cc * 16);
        }
        __syncthreads();
#pragma unroll 1
        for (int cc = 0; cc < 4; cc++) {
            const char* cb = (const char*)lds + cc * 4112;
            float iv0[16], iv1[16];
#pragma unroll
            for (int q = 0; q < 16; q++) {
                iv0[q] = *(const float*)(cb + offs[0][q]);
                iv1[q] = *(const float*)(cb + offs[1][q]);
            }
            const float* wb = &lds[4112 + cc*1024 + g*512];   // wave-uniform base
#pragma unroll
            for (int o = 0; o < 32; o++) {
                float wt[16];
                *(float4*)&wt[0]  = *(const float4*)(wb + o*16);
                *(float4*)&wt[4]  = *(const float4*)(wb + o*16 + 4);
                *(float4*)&wt[8]  = *(const float4*)(wb + o*16 + 8);
                *(float4*)&wt[12] = *(const float4*)(wb + o*16 + 12);
#pragma unroll
                for (int q = 0; q < 16; q++) {
                    acc0[o] = fmaf(iv0[q], wt[q], acc0[o]);
                    acc1[o] = fmaf(iv1[q], wt[q], acc1[o]);
                }
            }
        }
    }
    float* op = out + (size_t)n * 16384;
#pragma unroll
    for (int o = 0; o < 32; o++) {
        op[(g*32 + o) * 256 + y0*16 + x]       = acc0[o];
        op[(g*32 + o) * 256 + (y0+8)*16 + x]   = acc1[o];
    }
}

// ------- conv3: 64x16x16 -> 128x8x8, 1 sample/block, 8 groups x 16 oc ------
__global__ __launch_bounds__(256) void conv3_r(const float* __restrict__ in,
    const float* __restrict__ w, const float* __restrict__ bias, float* __restrict__ out)
{
    __shared__ __align__(16) float lds[9232];    // 4*260 input + 8192 wt
    int n   = blockIdx.x;
    int tid = threadIdx.x;
    int g   = tid >> 5;                  // 0..7 -> oc group (16 oc)
    int slot= tid & 31;
    int x   = slot & 7, y0 = slot >> 3;  // x 0..7, y0 0..3

    int offs[2][16];
#pragma unroll
    for (int p = 0; p < 2; p++) {
        int y = y0 + 4 * p;
#pragma unroll
        for (int ky = 0; ky < 4; ky++) {
            int yi = 2 * y - 1 + ky;
#pragma unroll
            for (int kx = 0; kx < 4; kx++) {
                int xi = 2 * x - 1 + kx;
                bool ok = ((unsigned)yi < 16u) && ((unsigned)xi < 16u);
                int rot = ((xi >> 2) + (yi & 3)) & 3;
                int foff = yi * 16 + rot * 4 + (xi & 3);
                offs[p][ky*4+kx] = ok ? (4 + foff) * 4 : 0;   // bytes; 0 = zero slot
            }
        }
    }
    if (tid < 16) lds[(tid >> 2) * 260 + (tid & 3)] = 0.f;    // zero slots

    float acc0[16], acc1[16];
#pragma unroll
    for (int i = 0; i < 16; i++) { float bv = bias[g*16 + i]; acc0[i] = bv; acc1[i] = bv; }

    const float* ip = in + (size_t)n * 16384;
#pragma unroll 1
    for (int ch = 0; ch < 16; ch++) {             // 16 chunks x 4 channels
        __syncthreads();
        {   // stage input: 4 ch x 256 fl, rotated rows (1 f4/thread)
            const float4* gs = (const float4*)(ip + (ch << 10));
            int cc = tid >> 6, r = (tid >> 2) & 15, s4 = tid & 3;
            int rs = (s4 + (r & 3)) & 3;
            *(float4*)&lds[cc*260 + 4 + r*16 + rs*4] = gs[tid];
            // stage weights: 4 ch x 128 oc x 16 (8 f4/thread)
            int oc = tid >> 1, h = tid & 1;
            const float* wg = w + (size_t)oc * 1024 + (ch << 6) + h * 8;
#pragma unroll
            for (int c2 = 0; c2 < 4; c2++) {
                *(float4*)&lds[1040 + c2*2048 + oc*16 + h*8]     = *(const float4*)(wg + c2*16);
                *(float4*)&lds[1040 + c2*2048 + oc*16 + h*8 + 4] = *(const float4*)(wg + c2*16 + 4);
            }
        }
        __syncthreads();
#pragma unroll 1
        for (int cc = 0; cc < 4; cc++) {
            const char* cb = (const char*)lds + cc * 1040;
            float iv0[16], iv1[16];
#pragma unroll
            for (int q = 0; q < 16; q++) {
                iv0[q] = *(const float*)(cb + offs[0][q]);
                iv1[q] = *(const float*)(cb + offs[1][q]);
            }
            const float* wb = &lds[1040 + cc*2048 + g*256];   // half-wave-uniform
#pragma unroll
            for (int o = 0; o < 16; o++) {
                float wt[16];
                *(float4*)&wt[0]  = *(const float4*)(wb + o*16);
                *(float4*)&wt[4]  = *(const float4*)(wb + o*16 + 4);
                *(float4*)&wt[8]  = *(const float4*)(wb + o*16 + 8);
                *(float4*)&wt[12] = *(const float4*)(wb + o*16 + 12);
#pragma unroll
                for (int q = 0; q < 16; q++) {
                    acc0[o] = fmaf(iv0[q], wt[q], acc0[o]);
                    acc1[o] = fmaf(iv1[q], wt[q], acc1[o]);
                }
            }
        }
    }
    float* op = out + (size_t)n * 8192;
#pragma unroll
    for (int o = 0; o < 16; o++) {
        op[(g*16 + o) * 64 + slot]      = acc0[o];
        op[(g*16 + o) * 64 + slot + 32] = acc1[o];
    }
}

// ----------------- conv4 + LN4 + SiLU: 128x8x8 -> 256x4x4 ------------------
__global__ __launch_bounds__(256) void conv4_f(const float* __restrict__ in,
    const float* __restrict__ w, const float* __restrict__ bias,
    const float* __restrict__ g, const float* __restrict__ bet, float* __restrict__ out)
{
    int n  = blockIdx.x;
    int oc = threadIdx.x;                 // 0..255
    const float* ip = in + (size_t)n * 8192;
    const float* wr = w + (size_t)oc * 2048;

    float acc[16];
#pragma unroll
    for (int s = 0; s < 16; s++) acc[s] = bias[oc];

    for (int c = 0; c < 128; c++) {
        const float* ic = ip + c * 64;     // uniform base -> s_load, CSE'd
        const float* wc = wr + c * 16;
        float wf[16];
#pragma unroll
        for (int q = 0; q < 16; q += 4) {
            float4 v = *(const float4*)(wc + q);
            wf[q] = v.x; wf[q+1] = v.y; wf[q+2] = v.z; wf[q+3] = v.w;
        }
#pragma unroll
        for (int y = 0; y < 4; y++)
#pragma unroll
        for (int x = 0; x < 4; x++) {
            float a = acc[y * 4 + x];
#pragma unroll
            for (int ky = 0; ky < 4; ky++) {
                int yy = 2 * y - 1 + ky;
                if (yy < 0 || yy > 7) continue;      // folds at compile time
#pragma unroll
                for (int kx = 0; kx < 4; kx++) {
                    int xx = 2 * x - 1 + kx;
                    if (xx < 0 || xx > 7) continue;
                    a += wf[ky * 4 + kx] * ic[yy * 8 + xx];
                }
            }
            acc[y * 4 + x] = a;
        }
    }
    float s = 0.f, s2 = 0.f;
#pragma unroll
    for (int q = 0; q < 16; q++) { s += acc[q]; s2 += acc[q] * acc[q]; }
    float mean, rstd;
    block_stats_256(s, s2, 4096, mean, rstd);

    float* op = out + (size_t)n * 4096;
#pragma unroll
    for (int q = 0; q < 16; q++) {
        int flat = oc * 16 + q;
        float v = (acc[q] - mean) * rstd * g[flat] + bet[flat];
        op[flat] = silu_f(v);
    }
}

// -------- transpose fc_w [256][4096] -> fcwT [4096][256] (LDS-tiled) -------
__global__ __launch_bounds__(256) void trfc_k(const float* __restrict__ w,
                                              float* __restrict__ wt)
{
    __shared__ float t[32][33];
    int bk = blockIdx.x * 32;             // k dim (4096)
    int bj = blockIdx.y * 32;             // j dim (256)
    int lx = threadIdx.x & 31, ly = threadIdx.x >> 5;   // 32 x 8
#pragma unroll
    for (int s = 0; s < 4; s++)
        t[ly + 8*s][lx] = w[(size_t)(bj + ly + 8*s) * 4096 + bk + lx];
    __syncthreads();
#pragma unroll
    for (int s = 0; s < 4; s++)
        wt[(size_t)(bk + ly + 8*s) * 256 + bj + lx] = t[lx][ly + 8*s];
}

// ---------------- fc: [S,4096] @ wT[4096][256], coalesced ------------------
__global__ __launch_bounds__(256) void fc_k2(const float* __restrict__ a,
    const float* __restrict__ wT, const float* __restrict__ bias, float* __restrict__ o)
{
    int n0 = blockIdx.x * 8;              // chunk-local rows
    int j  = threadIdx.x;
    float acc[8];
#pragma unroll
    for (int r = 0; r < 8; r++) acc[r] = 0.f;
    for (int k = 0; k < 4096; k += 4) {
        float wv0 = wT[(size_t)k * 256 + j];
        float wv1 = wT[(size_t)(k+1) * 256 + j];
        float wv2 = wT[(size_t)(k+2) * 256 + j];
        float wv3 = wT[(size_t)(k+3) * 256 + j];
#pragma unroll
        for (int r = 0; r < 8; r++) {
            const float* ar = a + (size_t)(n0 + r) * 4096 + k;   // uniform -> s_load x4
            acc[r] += wv0*ar[0] + wv1*ar[1] + wv2*ar[2] + wv3*ar[3];
        }
    }
    float bj = bias[j];
#pragma unroll
    for (int r = 0; r < 8; r++) o[(size_t)(n0 + r) * 256 + j] = acc[r] + bj;
}

// ----------- Fpost[n,j] = post_b[j] + feats[n,:] @ post_w[j,128:384] -------
__global__ __launch_bounds__(256) void fpost_k(const float* __restrict__ f,
    const float* __restrict__ w, const float* __restrict__ bias, float* __restrict__ o)
{
    int n0 = blockIdx.x * 4;
    int tid = threadIdx.x;
    float acc[4][4];
#pragma unroll
    for (int r = 0; r < 4; r++)
#pragma unroll
        for (int jj = 0; jj < 4; jj++) acc[r][jj] = 0.f;
    for (int k = 0; k < 256; k += 4) {
        float4 wv[4];
#pragma unroll
        for (int jj = 0; jj < 4; jj++)
            wv[jj] = *(const float4*)(w + (size_t)(tid + jj * 256) * 384 + 128 + k);
#pragma unroll
        for (int r = 0; r < 4; r++) {
            const float* fr = f + (size_t)(n0 + r) * 256 + k;    // uniform
            float a0 = fr[0], a1 = fr[1], a2 = fr[2], a3 = fr[3];
#pragma unroll
            for (int jj = 0; jj < 4; jj++)
                acc[r][jj] += wv[jj].x*a0 + wv[jj].y*a1 + wv[jj].z*a2 + wv[jj].w*a3;
        }
    }
#pragma unroll
    for (int jj = 0; jj < 4; jj++) {
        float bj = bias[tid + jj * 256];
#pragma unroll
        for (int r = 0; r < 4; r++)
            o[(size_t)(n0 + r) * 1024 + tid + jj * 256] = acc[r][jj] + bj;
    }
}

// ----------- prior[n,j] = prior_b[j] + h[n,:] @ prior_w[j,:] ---------------
__global__ __launch_bounds__(256) void prior_k(const float* __restrict__ h,
    const float* __restrict__ w, const float* __restrict__ bias, float* __restrict__ o)
{
    int n0 = blockIdx.x * 4;
    int tid = threadIdx.x;
    float acc[4][4];
#pragma unroll
    for (int r = 0; r < 4; r++)
#pragma unroll
        for (int jj = 0; jj < 4; jj++) acc[r][jj] = 0.f;
    for (int k = 0; k < 128; k += 4) {
        float4 wv[4];
#pragma unroll
        for (int jj = 0; jj < 4; jj++)
            wv[jj] = *(const float4*)(w + (size_t)(tid + jj * 256) * 128 + k);
#pragma unroll
        for (int r = 0; r < 4; r++) {
            const float* hr = h + (size_t)(n0 + r) * 128 + k;    // uniform
            float a0 = hr[0], a1 = hr[1], a2 = hr[2], a3 = hr[3];
#pragma unroll
            for (int jj = 0; jj < 4; jj++)
                acc[r][jj] += wv[jj].x*a0 + wv[jj].y*a1 + wv[jj].z*a2 + wv[jj].w*a3;
        }
    }
#pragma unroll
    for (int jj = 0; jj < 4; jj++) {
        float bj = bias[tid + jj * 256];
#pragma unroll
        for (int r = 0; r < 4; r++)
            o[(size_t)(n0 + r) * 1024 + tid + jj * 256] = acc[r][jj] + bj;
    }
}

// ----------- Ai[n,j] = bih[j] + actions[n,:] @ wih[j,1024:1030] ------------
__global__ __launch_bounds__(128) void ai_k(const float* __restrict__ act,
    const float* __restrict__ wih, const float* __restrict__ bih, float* __restrict__ o)
{
    int n = blockIdx.x;
    int j = blockIdx.y * 128 + threadIdx.x;     // 0..383
    const float* ar = act + (size_t)n * 6;       // uniform
    const float* wr = wih + (size_t)j * 1030 + 1024;
    float acc = bih[j];
#pragma unroll
    for (int k = 0; k < 6; k++) acc += ar[k] * wr[k];
    o[(size_t)n * 384 + j] = acc;
}

// ----------- wihT[k,j] = wih[j,k]  (z-part only, k<1024) -------------------
__global__ __launch_bounds__(256) void tr_k(const float* __restrict__ wih,
                                            float* __restrict__ wt)
{
    int g = blockIdx.x * 256 + threadIdx.x;      // 0..393215
    int k = g / 384;
    int j = g - k * 384;
    wt[g] = wih[(size_t)j * 1030 + k];
}

// ----- whhV[k4][j][c] = whh[j][4*k4+c]  (float4-packed, coalesced matvec) --
__global__ __launch_bounds__(256) void tr_whh_k(const float* __restrict__ whh,
                                                float* __restrict__ wt)
{
    int g = blockIdx.x * 256 + threadIdx.x;      // 0..49151
    int c  = g & 3;
    int jk = g >> 2;                             // 0..12287
    int j  = jk % 384;
    int k4 = jk / 384;                           // 0..31
    wt[g] = whh[(size_t)j * 128 + k4 * 4 + c];
}

// ----- pwV[k4][j][c] = post_w[j][4*k4+c] (h-cols only, float4-packed) ------
__global__ __launch_bounds__(256) void tr_pw_k(const float* __restrict__ pw,
                                               float* __restrict__ wt)
{
    int g = blockIdx.x * 256 + threadIdx.x;      // 0..131071
    int c  = g & 3;
    int jk = g >> 2;                             // 0..32767
    int j  = jk & 1023;
    int k4 = jk >> 10;                           // 0..31
    wt[g] = pw[(size_t)j * 384 + k4 * 4 + c];
}

// ------------------------- GRU recurrence (1 block / sample) ---------------
// R8: k4-major float4 weight layouts -> 32 coalesced float4 loads per output
// column (was 128 scalar loads); unroll-8 keeps ~16 loads in flight. h read
// as broadcast float4 from LDS. 2 outputs/thread in post; in-register
// shfl_xor argmax (first-max tiebreak); 3 barriers/step.
__global__ __launch_bounds__(1024) void gru_k(const float* __restrict__ wihT,
    const float* __restrict__ whhV, const float* __restrict__ bhh,
    const float* __restrict__ ai, const float* __restrict__ fpost,
    const float* __restrict__ pwV, float* __restrict__ out)
{
    float* out_post = out + 1048576;
    float* out_h    = out + 2097152;
    float* out_z    = out + 2228224;
    int b   = blockIdx.x;
    int tid = threadIdx.x;
    __shared__ __align__(16) float h[128];
    __shared__ float gi[384], gh[384];
    __shared__ int idx[32];
    if (tid < 128) h[tid] = 0.f;
    __syncthreads();

    const float4* h4  = (const float4*)h;
    const float4* wv4 = (const float4*)whhV;
    const float4* pv4 = (const float4*)pwV;

    for (int t = 0; t < 64; t++) {
        int n = b * 64 + t;
        if (tid < 384) {
            float a = ai[(size_t)n * 384 + tid];
            if (t > 0) {
#pragma unroll 8
                for (int c = 0; c < 32; c++)
                    a += wihT[(size_t)(c * 32 + idx[c]) * 384 + tid];
            }
            gi[tid] = a;
            float a2 = bhh[tid];
#pragma unroll 8
            for (int k4 = 0; k4 < 32; k4++) {
                float4 wq = wv4[k4 * 384 + tid];     // coalesced 16B/lane
                float4 hq = h4[k4];                  // broadcast b128
                a2 += wq.x*hq.x + wq.y*hq.y + wq.z*hq.z + wq.w*hq.w;
            }
            gh[tid] = a2;
        }
        __syncthreads();                                    // B1
        if (tid < 128) {
            float r  = sigm_f(gi[tid] + gh[tid]);
            float u  = sigm_f(gi[128 + tid] + gh[128 + tid]);
            float nn = tanhf(gi[256 + tid] + r * gh[256 + tid]);
            float hn = (1.f - u) * nn + u * h[tid];
            h[tid] = hn;
            out_h[(size_t)n * 128 + tid] = hn;
        }
        __syncthreads();                                    // B2
        if (tid < 512) {
            // outputs j0 = tid, j1 = tid + 512 (chunks c0 = tid>>5, c0+16)
            float a0 = fpost[(size_t)n * 1024 + tid];
            float a1 = fpost[(size_t)n * 1024 + 512 + tid];
#pragma unroll 8
            for (int k4 = 0; k4 < 32; k4++) {
                float4 hq = h4[k4];                  // reused for both outputs
                float4 w0 = pv4[k4 * 1024 + tid];
                float4 w1 = pv4[k4 * 1024 + 512 + tid];
                a0 += w0.x*hq.x + w0.y*hq.y + w0.z*hq.z + w0.w*hq.w;
                a1 += w1.x*hq.x + w1.y*hq.y + w1.z*hq.z + w1.w*hq.w;
            }
            out_post[(size_t)n * 1024 + tid]       = a0;
            out_post[(size_t)n * 1024 + 512 + tid] = a1;

            // first-max argmax over each 32-lane chunk, in-register butterfly
            float b0 = a0, b1 = a1;
            int i0 = tid & 31, i1 = tid & 31;
#pragma unroll
            for (int m = 16; m >= 1; m >>= 1) {
                float ob0 = __shfl_xor(b0, m);
                int   oi0 = __shfl_xor(i0, m);
                float ob1 = __shfl_xor(b1, m);
                int   oi1 = __shfl_xor(i1, m);
                if (ob0 > b0 || (ob0 == b0 && oi0 < i0)) { b0 = ob0; i0 = oi0; }
                if (ob1 > b1 || (ob1 == b1 && oi1 < i1)) { b1 = ob1; i1 = oi1; }
            }
            out_z[(size_t)n * 1024 + tid]       = ((tid & 31) == i0) ? 1.f : 0.f;
            out_z[(size_t)n * 1024 + 512 + tid] = ((tid & 31) == i1) ? 1.f : 0.f;
            if ((tid & 31) == 0) {
                idx[tid >> 5]        = i0;
                idx[(tid >> 5) + 16] = i1;
            }
        }
        __syncthreads();                                    // B3
    }
}

// ---------------------------------------------------------------------------
extern "C" void kernel_launch(void* const* d_in, const int* in_sizes, int n_in,
                              void* d_out, int out_size, void* d_ws, size_t ws_size,
                              hipStream_t stream)
{
    const float* states  = (const float*)d_in[0];
    const float* actions = (const float*)d_in[1];
    const float* c1w = (const float*)d_in[2];  const float* c1b = (const float*)d_in[3];
    const float* l1g = (const float*)d_in[4];  const float* l1b = (const float*)d_in[5];
    const float* c2w = (const float*)d_in[6];  const float* c2b = (const float*)d_in[7];
    const float* l2g = (const float*)d_in[8];  const float* l2b = (const float*)d_in[9];
    const float* c3w = (const float*)d_in[10]; const float* c3b = (const float*)d_in[11];
    const float* l3g = (const float*)d_in[12]; const float* l3b = (const float*)d_in[13];
    const float* c4w = (const float*)d_in[14]; const float* c4b = (const float*)d_in[15];
    const float* l4g = (const float*)d_in[16]; const float* l4b = (const float*)d_in[17];
    const float* fcw = (const float*)d_in[18]; const float* fcb = (const float*)d_in[19];
    const float* wih = (const float*)d_in[20]; const float* whh = (const float*)d_in[21];
    const float* bih = (const float*)d_in[22]; const float* bhh = (const float*)d_in[23];
    const float* prw = (const float*)d_in[24]; const float* prb = (const float*)d_in[25];
    const float* pw  = (const float*)d_in[26]; const float* pb  = (const float*)d_in[27];

    float* out = (float*)d_out;
    float* ws  = (float*)d_ws;

    // ---- adaptive chunking: largest S whose footprint fits ws_size --------
    // footprint = (S*49152 + fixed 3,325,952) floats
    size_t S = 64;
    {
        const size_t cands[4] = {1024, 512, 256, 128};
        for (int i = 0; i < 4; i++) {
            size_t need = (cands[i] * 49152ull + 3325952ull) * 4ull;
            if (need <= ws_size) { S = cands[i]; break; }
        }
    }
    int C = (int)(1024 / S);

    float* bufA  = ws;                       // S*32768
    float* bufB  = bufA + S * 32768;         // S*16384
    float* feats = bufB + S * 16384;         //   262,144
    float* fpost = feats + 262144;           // 1,048,576
    float* aibuf = fpost + 1048576;          //   393,216
    float* wihT  = aibuf + 393216;           //   393,216
    float* fcwT  = wihT + 393216;            // 1,048,576
    float* whhV  = fcwT + 1048576;           //    49,152
    float* pwV   = whhV + 49152;             //   131,072

    trfc_k<<<dim3(128, 8), 256, 0, stream>>>(fcw, fcwT);
    tr_whh_k<<<192, 256, 0, stream>>>(whh, whhV);
    tr_pw_k<<<512, 256, 0, stream>>>(pw, pwV);

    for (int cc = 0; cc < C; cc++) {
        size_t n0 = (size_t)cc * S;
        conv1_k<<<dim3((unsigned)S, 4), 256, 0, stream>>>(states + n0 * 12288, c1w, c1b, bufA);
        ln_fuse_k<<<(unsigned)S, 256, 0, stream>>>(bufA, l1g, l1b, 32768);
        conv2_r<<<(unsigned)S, 256, 0, stream>>>(bufA, c2w, c2b, bufB);
        ln_fuse_k<<<(unsigned)S, 256, 0, stream>>>(bufB, l2g, l2b, 16384);
        conv3_r<<<(unsigned)S, 256, 0, stream>>>(bufB, c3w, c3b, bufA);
        ln_fuse_k<<<(unsigned)S, 256, 0, stream>>>(bufA, l3g, l3b, 8192);
        conv4_f<<<(unsigned)S, 256, 0, stream>>>(bufA, c4w, c4b, l4g, l4b, bufB);
        fc_k2<<<(unsigned)(S / 8), 256, 0, stream>>>(bufB, fcwT, fcb, feats + n0 * 256);
    }

    fpost_k<<<256, 256, 0, stream>>>(feats, pw, pb, fpost);
    ai_k<<<dim3(1024, 3), 128, 0, stream>>>(actions, wih, bih, aibuf);
    tr_k<<<1536, 256, 0, stream>>>(wih, wihT);

    gru_k<<<16, 1024, 0, stream>>>(wihT, whhV, bhh, aibuf, fpost, pwV, out);
    prior_k<<<256, 256, 0, stream>>>(out + 2097152, prw, prb, out);
}